// Round 8
// baseline (369.987 us; speedup 1.0000x reference)
//
#include <hip/hip_runtime.h>
#include <math.h>

// ---------------------------------------------------------------------------
// Mamba block forward. b=4, l=1024, dm=1024, di=2048, n=16, r=64.
// GEMMs: pure-bf16 MFMA (hi/lo split, 3 MFMA/product), inputs pre-converted.
// R8: gemm256 K-loop split into 4 phases (24 MFMA each) with per-phase
//     barrier + lgkmcnt(0) + setprio clusters (T3/T5); counted vmcnt kept.
// Scan: chunked 3-phase (32 chunks x 32 steps).
// ---------------------------------------------------------------------------

typedef __bf16 bf16x8 __attribute__((ext_vector_type(8)));
typedef __bf16 bf16x4 __attribute__((ext_vector_type(4)));
typedef float f32x4 __attribute__((ext_vector_type(4)));

__device__ __forceinline__ void gload16(const void* g, void* lds_p) {
  __builtin_amdgcn_global_load_lds((const __attribute__((address_space(1))) void*)g,
                                   (__attribute__((address_space(3))) void*)lds_p,
                                   16, 0, 0);
}

// ---------------- f32 -> bf16 hi/lo conversion ----------------
__device__ __forceinline__ void hilo4(float4 v, bf16x4& h, bf16x4& l) {
  h[0] = (__bf16)v.x; l[0] = (__bf16)(v.x - (float)h[0]);
  h[1] = (__bf16)v.y; l[1] = (__bf16)(v.y - (float)h[1]);
  h[2] = (__bf16)v.z; l[2] = (__bf16)(v.z - (float)h[2]);
  h[3] = (__bf16)v.w; l[3] = (__bf16)(v.w - (float)h[3]);
}

// One fused conversion pass over all five f32 tensors + xpw zero-pad.
__global__ __launch_bounds__(256) void cvt_all(
    const float* __restrict__ hidden, const float* __restrict__ in_proj_w,
    const float* __restrict__ x_proj_w, const float* __restrict__ dt_proj_w,
    const float* __restrict__ out_proj_w,
    __bf16* __restrict__ hid_h, __bf16* __restrict__ hid_l,
    __bf16* __restrict__ inw_h, __bf16* __restrict__ inw_l,
    __bf16* __restrict__ xpw_h, __bf16* __restrict__ xpw_l,
    __bf16* __restrict__ dtw_h, __bf16* __restrict__ dtw_l,
    __bf16* __restrict__ ow_h,  __bf16* __restrict__ ow_l)
{
  int i = blockIdx.x * 256 + threadIdx.x;
  const float* s; __bf16 *H, *L; int off;
  if (i < 1048576)      { s = hidden;     H = hid_h; L = hid_l; off = i; }
  else if (i < 2097152) { s = in_proj_w;  H = inw_h; L = inw_l; off = i - 1048576; }
  else if (i < 2146304) { s = x_proj_w;   H = xpw_h; L = xpw_l; off = i - 2097152; }
  else if (i < 2179072) { s = dt_proj_w;  H = dtw_h; L = dtw_l; off = i - 2146304; }
  else if (i < 2703360) { s = out_proj_w; H = ow_h;  L = ow_l;  off = i - 2179072; }
  else {  // zero-pad xpw rows 96..127
    int j = i - 2703360;
    bf16x4 z = {};
    ((bf16x4*)(xpw_h + 196608))[j] = z;
    ((bf16x4*)(xpw_l + 196608))[j] = z;
    return;
  }
  float4 v = ((const float4*)s)[off];
  bf16x4 h, l;
  hilo4(v, h, l);
  ((bf16x4*)H)[off] = h;
  ((bf16x4*)L)[off] = l;
}

// ---------------------------------------------------------------------------
// Big NT GEMM: 256x256 block, 8 waves, wave tile 128x64 (acc 8x4 f32x4).
// C = AhBh + AhBl + AlBh, f32 accumulate. M,N % 256 == 0 (no guards).
// LDS: dynamic 128 KB = 2 bufs x 4 tiles(Ah,Al,Bh,Bl) x 256x32 bf16.
// K-loop: stage t+1 (8 gloads) -> vmcnt(8) -> barrier -> 4 phases, each
// {ds_read frags; lgkmcnt(0); setprio(1); 24 MFMA; setprio(0); barrier}.
// grid (N/256, M/256, S): z = split-K segment of kseg; partial slabs in C.
// gridDim.x*gridDim.y must be a multiple of 8 (XCD swizzle).
// ---------------------------------------------------------------------------
__global__ __launch_bounds__(512, 1) void gemm256(
    const __bf16* __restrict__ Ah, const __bf16* __restrict__ Al,
    const __bf16* __restrict__ Bh, const __bf16* __restrict__ Bl,
    float* __restrict__ C, int lda, int ldb, int ldc, int kseg)
{
  extern __shared__ __align__(16) __bf16 lds[];   // 2 x 32768 elements

  const int tid = threadIdx.x;
  const int lane = tid & 63;
  const int laneL = lane & 15;
  const int laneH = lane >> 4;
  const int wave = tid >> 6;        // 0..7
  const int wm = wave >> 2;         // 0..1 (M half)
  const int wn = wave & 3;          // 0..3 (N quarter)

  // bijective XCD swizzle over the (x,y) grid plane
  const int nbx = gridDim.x;
  const int nwg = nbx * gridDim.y;
  int wg = blockIdx.y * nbx + blockIdx.x;
  wg = (wg & 7) * (nwg >> 3) + (wg >> 3);
  const int row0 = (wg / nbx) * 256;
  const int col0 = (wg % nbx) * 256;
  const int k0base = blockIdx.z * kseg;

  // staging role: wave -> (matrix, row-half)
  const int mat = wave >> 1;        // 0 Ah, 1 Al, 2 Bh, 3 Bl
  const int half = wave & 1;
  const __bf16* src = (mat == 0) ? Ah : (mat == 1) ? Al : (mat == 2) ? Bh : Bl;
  const int srcLd = (mat < 2) ? lda : ldb;
  const int srcRow0 = ((mat < 2) ? row0 : col0) + half * 128;
  const int lr = lane >> 2;          // 0..15
  const int ls = lane & 3;           // 0..3
  const int ksl = (ls ^ ((lr >> 1) & 3)) * 8;   // pre-swizzled k offset
  const __bf16* gbase = src + (size_t)(srcRow0 + lr) * srcLd + ksl;
  const int dstoff = mat * 8192 + half * 4096 + lane * 8;

  const int rsw = (laneL >> 1) & 3;  // read-side swizzle
  f32x4 acc[8][4] = {};
  const int nk = kseg >> 5;

  // prologue: stage tile 0 into buffer 0
  {
    const __bf16* g = gbase + k0base;
    __bf16* dst = lds + dstoff;
#pragma unroll
    for (int i = 0; i < 8; i++)
      gload16(g + (size_t)i * 16 * srcLd, dst + i * 512);
  }

  int cur = 0;
  for (int t = 0; t < nk; t++) {
    if (t + 1 < nk) {
      const __bf16* g = gbase + k0base + (t + 1) * 32;
      __bf16* dst = lds + (cur ^ 1) * 32768 + dstoff;
#pragma unroll
      for (int i = 0; i < 8; i++)
        gload16(g + (size_t)i * 16 * srcLd, dst + i * 512);
      asm volatile("s_waitcnt vmcnt(8)" ::: "memory");  // tile t's loads done
    } else {
      asm volatile("s_waitcnt vmcnt(0)" ::: "memory");
    }
    __builtin_amdgcn_s_barrier();      // buf[cur] = tile t visible to all

    const __bf16* base = lds + cur * 32768;
    const __bf16* sAh = base;
    const __bf16* sAl = base + 8192;
    const __bf16* sBh = base + 16384;
    const __bf16* sBl = base + 24576;

    bf16x8 bh[4], bl[4];
#pragma unroll
    for (int p = 0; p < 4; p++) {
      if (p == 0) {
#pragma unroll
        for (int j = 0; j < 4; j++) {
          int off = (wn * 64 + j * 16 + laneL) * 32 + ((laneH ^ rsw) << 3);
          bh[j] = *(const bf16x8*)&sBh[off];
          bl[j] = *(const bf16x8*)&sBl[off];
        }
      }
      int off0 = (wm * 128 + (2 * p) * 16 + laneL) * 32 + ((laneH ^ rsw) << 3);
      int off1 = off0 + 16 * 32;
      bf16x8 ah0 = *(const bf16x8*)&sAh[off0];
      bf16x8 al0 = *(const bf16x8*)&sAl[off0];
      bf16x8 ah1 = *(const bf16x8*)&sAh[off1];
      bf16x8 al1 = *(const bf16x8*)&sAl[off1];
      asm volatile("s_waitcnt lgkmcnt(0)" ::: "memory");
      __builtin_amdgcn_sched_barrier(0);
      __builtin_amdgcn_s_setprio(1);
#pragma unroll
      for (int j = 0; j < 4; j++) {
        acc[2*p][j]   = __builtin_amdgcn_mfma_f32_16x16x32_bf16(ah0, bh[j], acc[2*p][j], 0, 0, 0);
        acc[2*p][j]   = __builtin_amdgcn_mfma_f32_16x16x32_bf16(ah0, bl[j], acc[2*p][j], 0, 0, 0);
        acc[2*p][j]   = __builtin_amdgcn_mfma_f32_16x16x32_bf16(al0, bh[j], acc[2*p][j], 0, 0, 0);
        acc[2*p+1][j] = __builtin_amdgcn_mfma_f32_16x16x32_bf16(ah1, bh[j], acc[2*p+1][j], 0, 0, 0);
        acc[2*p+1][j] = __builtin_amdgcn_mfma_f32_16x16x32_bf16(ah1, bl[j], acc[2*p+1][j], 0, 0, 0);
        acc[2*p+1][j] = __builtin_amdgcn_mfma_f32_16x16x32_bf16(al1, bh[j], acc[2*p+1][j], 0, 0, 0);
      }
      __builtin_amdgcn_s_setprio(0);
      __builtin_amdgcn_sched_barrier(0);
      __builtin_amdgcn_s_barrier();    // phase lockstep; last one guards re-stage
    }
    cur ^= 1;
  }

  float* Cz = C + (size_t)blockIdx.z * gridDim.y * 256 * ldc;
#pragma unroll
  for (int i = 0; i < 8; i++) {
    int rr = row0 + wm * 128 + i * 16 + laneH * 4;
#pragma unroll
    for (int j = 0; j < 4; j++) {
      int cc = col0 + wn * 64 + j * 16 + laneL;
#pragma unroll
      for (int r = 0; r < 4; r++)
        Cz[(size_t)(rr + r) * ldc + cc] = acc[i][j][r];
    }
  }
}

// ---------------------------------------------------------------------------
// Small NT GEMM (128x128, 4 waves) for x_proj / dt_proj. Unchanged.
// ---------------------------------------------------------------------------
__global__ __launch_bounds__(256, 2) void gemm3(
    const __bf16* __restrict__ Ah, const __bf16* __restrict__ Al,
    const __bf16* __restrict__ Bh, const __bf16* __restrict__ Bl,
    float* __restrict__ C, int lda, int ldb, int ldc, int kseg, int epi)
{
  __shared__ __align__(16) __bf16 lds[2][4][128 * 32];

  const int tid = threadIdx.x;
  const int lane = tid & 63;
  const int laneL = lane & 15;
  const int laneH = lane >> 4;
  const int wave = tid >> 6;
  const int wm = wave >> 1;
  const int wn = wave & 1;
  const int row0 = blockIdx.y * 128;
  const int col0 = blockIdx.x * 128;
  const int k0base = blockIdx.z * kseg;

  const __bf16* src = (wave == 0) ? Ah : (wave == 1) ? Al : (wave == 2) ? Bh : Bl;
  const int srcLd = (wave < 2) ? lda : ldb;
  const int srcRow0 = (wave < 2) ? row0 : col0;
  const int lr = lane >> 2;
  const int ls = lane & 3;
  const int ksl = (ls ^ ((lr >> 1) & 3)) * 8;
  const __bf16* gbase = src + (size_t)(srcRow0 + lr) * srcLd + ksl;

  const int rsw = (laneL >> 1) & 3;
  f32x4 acc[4][4] = {};
  const int nk = kseg >> 5;

  {
    const __bf16* g = gbase + k0base;
    __bf16* dst = &lds[0][wave][lane * 8];
#pragma unroll
    for (int i = 0; i < 8; i++)
      gload16(g + (size_t)i * 16 * srcLd, dst + i * 512);
  }

  int cur = 0;
  for (int t = 0; t < nk; t++) {
    if (t + 1 < nk) {
      const __bf16* g = gbase + k0base + (t + 1) * 32;
      __bf16* dst = &lds[cur ^ 1][wave][lane * 8];
#pragma unroll
      for (int i = 0; i < 8; i++)
        gload16(g + (size_t)i * 16 * srcLd, dst + i * 512);
      asm volatile("s_waitcnt vmcnt(8)" ::: "memory");
    } else {
      asm volatile("s_waitcnt vmcnt(0)" ::: "memory");
    }
    __builtin_amdgcn_s_barrier();
    __builtin_amdgcn_sched_barrier(0);

    const __bf16* sAh = lds[cur][0];
    const __bf16* sAl = lds[cur][1];
    const __bf16* sBh = lds[cur][2];
    const __bf16* sBl = lds[cur][3];

    bf16x8 ah[4], al[4], bh[4], bl[4];
#pragma unroll
    for (int i = 0; i < 4; i++) {
      int off = (wm * 64 + i * 16 + laneL) * 32 + ((laneH ^ rsw) << 3);
      ah[i] = *(const bf16x8*)&sAh[off];
      al[i] = *(const bf16x8*)&sAl[off];
    }
#pragma unroll
    for (int j = 0; j < 4; j++) {
      int off = (wn * 64 + j * 16 + laneL) * 32 + ((laneH ^ rsw) << 3);
      bh[j] = *(const bf16x8*)&sBh[off];
      bl[j] = *(const bf16x8*)&sBl[off];
    }
#pragma unroll
    for (int i = 0; i < 4; i++)
#pragma unroll
      for (int j = 0; j < 4; j++) {
        acc[i][j] = __builtin_amdgcn_mfma_f32_16x16x32_bf16(ah[i], bh[j], acc[i][j], 0, 0, 0);
        acc[i][j] = __builtin_amdgcn_mfma_f32_16x16x32_bf16(ah[i], bl[j], acc[i][j], 0, 0, 0);
        acc[i][j] = __builtin_amdgcn_mfma_f32_16x16x32_bf16(al[i], bh[j], acc[i][j], 0, 0, 0);
      }
    __builtin_amdgcn_sched_barrier(0);
    __builtin_amdgcn_s_barrier();
    cur ^= 1;
  }

  float* Cz = C + (size_t)blockIdx.z * gridDim.y * 128 * ldc;
#pragma unroll
  for (int i = 0; i < 4; i++) {
    int rr = row0 + wm * 64 + i * 16 + laneH * 4;
#pragma unroll
    for (int j = 0; j < 4; j++) {
      int cc = col0 + wn * 64 + j * 16 + laneL;
#pragma unroll
      for (int r = 0; r < 4; r++) {
        float v = acc[i][j][r];
        if (epi == 1) v = (v > 20.f) ? v : log1pf(expf(v));
        Cz[(size_t)(rr + r) * ldc + cc] = v;
      }
    }
  }
}

// ---------------- split-K reduces ----------------
__global__ __launch_bounds__(256) void reduce_xproj(
    const float* __restrict__ part, float* __restrict__ x_dbl,
    __bf16* __restrict__ dth, __bf16* __restrict__ dtl)
{
  int idx = blockIdx.x * 256 + threadIdx.x;   // 0 .. 4096*128-1
  int row = idx >> 7, col = idx & 127;
  float v = 0.f;
#pragma unroll
  for (int s = 0; s < 8; s++) v += part[(size_t)s * 524288 + idx];
  if (col < 96) x_dbl[(size_t)row * 96 + col] = v;
  if (col < 64) {
    __bf16 h = (__bf16)v;
    dth[(size_t)row * 64 + col] = h;
    dtl[(size_t)row * 64 + col] = (__bf16)(v - (float)h);
  }
}

// out_proj: 4 partials (4096 x 1024), sum -> out.
__global__ __launch_bounds__(256) void reduce_oproj(
    const float* __restrict__ part, float* __restrict__ out)
{
  int i = blockIdx.x * 256 + threadIdx.x;     // 0 .. 1048575 float4 units
  const float4 a = ((const float4*)part)[i];
  const float4 b = ((const float4*)part)[i + 1048576];
  const float4 c = ((const float4*)part)[i + 2097152];
  const float4 d = ((const float4*)part)[i + 3145728];
  float4 o = make_float4(a.x + b.x + c.x + d.x, a.y + b.y + c.y + d.y,
                         a.z + b.z + c.z + d.z, a.w + b.w + c.w + d.w);
  ((float4*)out)[i] = o;
}

// ---------------- depthwise causal conv + bias + silu (+ hi/lo out) --------
__global__ __launch_bounds__(256) void conv_silu_k(
    const float* __restrict__ xz, const float* __restrict__ conv_w,
    const float* __restrict__ conv_b, float* __restrict__ x,
    __bf16* __restrict__ xh, __bf16* __restrict__ xl)
{
  const int d = blockIdx.x * 256 + threadIdx.x;
  const int row = blockIdx.y;
  const int l = row & 1023;
  const float4 w = ((const float4*)conv_w)[d];
  float acc = conv_b[d];
  const float* base = xz + (size_t)row * 4096 + d;
  if (l >= 3) acc = fmaf(base[-3 * 4096], w.x, acc);
  if (l >= 2) acc = fmaf(base[-2 * 4096], w.y, acc);
  if (l >= 1) acc = fmaf(base[-1 * 4096], w.z, acc);
  acc = fmaf(base[0], w.w, acc);
  float s = acc / (1.f + expf(-acc));
  size_t o = (size_t)row * 2048 + d;
  x[o] = s;
  __bf16 h = (__bf16)s;
  xh[o] = h;
  xl[o] = (__bf16)(s - (float)h);
}

// ---------------- chunked selective scan ----------------
#define NCHK 32
#define LC   32
#define DB   64
#define LOG2E 1.44269504f

__global__ __launch_bounds__(256) void scan_chunk1(
    const float* __restrict__ delta, const float* __restrict__ x,
    const float* __restrict__ x_dbl, const float* __restrict__ A_log,
    float* __restrict__ Bacc, float* __restrict__ sdsum)
{
  __shared__ __align__(16) float sdel[LC][DB];
  __shared__ __align__(16) float sx[LC][DB];
  __shared__ __align__(16) float sB[LC][16];

  const int tid = threadIdx.x;
  const int dl = tid >> 2;
  const int ng = tid & 3;
  const int d0 = blockIdx.x * DB;
  const int c = blockIdx.y, b = blockIdx.z;
  const int d = d0 + dl;
  const size_t row0 = (size_t)b * 1024 + c * LC;

  float a2[4];
#pragma unroll
  for (int i = 0; i < 4; i++) a2[i] = -expf(A_log[d * 16 + ng * 4 + i]) * LOG2E;

#pragma unroll
  for (int i = 0; i < 2; i++) {
    int f = tid + i * 256;
    int lr = f >> 4, c4 = (f & 15) * 4;
    size_t g = (row0 + lr) * 2048 + d0 + c4;
    *(float4*)&sdel[lr][c4] = *(const float4*)&delta[g];
    *(float4*)&sx[lr][c4]   = *(const float4*)&x[g];
  }
  if (tid < 128) {
    int lr = tid >> 2, n4 = (tid & 3) * 4;
    *(float4*)&sB[lr][n4] = *(const float4*)&x_dbl[(row0 + lr) * 96 + 64 + n4];
  }
  __syncthreads();

  float q0 = 0.f, q1 = 0.f, q2 = 0.f, q3 = 0.f, sd = 0.f;
#pragma unroll
  for (int t = 0; t < LC; t++) {
    float dlt = sdel[t][dl];
    float dx = dlt * sx[t][dl];
    const float4 Bv = *(const float4*)&sB[t][ng * 4];
    q0 = exp2f(dlt * a2[0]) * q0 + dx * Bv.x;
    q1 = exp2f(dlt * a2[1]) * q1 + dx * Bv.y;
    q2 = exp2f(dlt * a2[2]) * q2 + dx * Bv.z;
    q3 = exp2f(dlt * a2[3]) * q3 + dx * Bv.w;
    sd += dlt;
  }
  size_t o = ((size_t)(b * NCHK + c) * 2048 + d) * 16 + ng * 4;
  *(float4*)&Bacc[o] = make_float4(q0, q1, q2, q3);
  if (ng == 0) sdsum[(size_t)(b * NCHK + c) * 2048 + d] = sd;
}

__global__ __launch_bounds__(256) void scan_chunk2(
    const float* __restrict__ A_log, const float* __restrict__ sdsum,
    float* __restrict__ BaccH)
{
  const int g = blockIdx.x * 256 + threadIdx.x;
  const int ng = g & 3;
  const int d = (g >> 2) & 2047;
  const int b = g >> 13;
  float a2[4];
#pragma unroll
  for (int i = 0; i < 4; i++) a2[i] = -expf(A_log[d * 16 + ng * 4 + i]) * LOG2E;
  float h0 = 0.f, h1 = 0.f, h2 = 0.f, h3 = 0.f;
#pragma unroll 4
  for (int c = 0; c < NCHK; c++) {
    size_t o = ((size_t)(b * NCHK + c) * 2048 + d) * 16 + ng * 4;
    const float4 Q = *(const float4*)&BaccH[o];
    const float sd = sdsum[(size_t)(b * NCHK + c) * 2048 + d];
    *(float4*)&BaccH[o] = make_float4(h0, h1, h2, h3);
    h0 = exp2f(sd * a2[0]) * h0 + Q.x;
    h1 = exp2f(sd * a2[1]) * h1 + Q.y;
    h2 = exp2f(sd * a2[2]) * h2 + Q.z;
    h3 = exp2f(sd * a2[3]) * h3 + Q.w;
  }
}

__global__ __launch_bounds__(256) void scan_chunk3(
    const float* __restrict__ delta, const float* __restrict__ x,
    const float* __restrict__ xz, const float* __restrict__ x_dbl,
    const float* __restrict__ A_log, const float* __restrict__ Dvec,
    const float* __restrict__ Hstart,
    __bf16* __restrict__ yh, __bf16* __restrict__ yl)
{
  __shared__ __align__(16) float sdel[LC][DB];
  __shared__ __align__(16) float sx[LC][DB];
  __shared__ __align__(16) float szo[LC][DB];
  __shared__ __align__(16) float sB[LC][16];
  __shared__ __align__(16) float sC[LC][16];

  const int tid = threadIdx.x;
  const int dl = tid >> 2;
  const int ng = tid & 3;
  const int d0 = blockIdx.x * DB;
  const int c = blockIdx.y, b = blockIdx.z;
  const int d = d0 + dl;
  const size_t row0 = (size_t)b * 1024 + c * LC;

  float a2[4];
#pragma unroll
  for (int i = 0; i < 4; i++) a2[i] = -expf(A_log[d * 16 + ng * 4 + i]) * LOG2E;
  const float Dd = Dvec[d];

#pragma unroll
  for (int i = 0; i < 2; i++) {
    int f = tid + i * 256;
    int lr = f >> 4, c4 = (f & 15) * 4;
    size_t g = (row0 + lr) * 2048 + d0 + c4;
    *(float4*)&sdel[lr][c4] = *(const float4*)&delta[g];
    *(float4*)&sx[lr][c4]   = *(const float4*)&x[g];
    *(float4*)&szo[lr][c4]  = *(const float4*)&xz[(row0 + lr) * 4096 + 2048 + d0 + c4];
  }
  {
    int which = tid >> 7;
    int f = tid & 127;
    int lr = f >> 2, n4 = (f & 3) * 4;
    float4 v = *(const float4*)&x_dbl[(row0 + lr) * 96 + 64 + which * 16 + n4];
    if (which == 0) *(float4*)&sB[lr][n4] = v;
    else            *(float4*)&sC[lr][n4] = v;
  }
  __syncthreads();

  size_t ho = ((size_t)(b * NCHK + c) * 2048 + d) * 16 + ng * 4;
  const float4 hv = *(const float4*)&Hstart[ho];
  float h0 = hv.x, h1 = hv.y, h2 = hv.z, h3 = hv.w;

#pragma unroll
  for (int t = 0; t < LC; t++) {
    float dlt = sdel[t][dl];
    float xv = sx[t][dl];
    float dx = dlt * xv;
    const float4 Bv = *(const float4*)&sB[t][ng * 4];
    const float4 Cv = *(const float4*)&sC[t][ng * 4];
    float acc;
    h0 = exp2f(dlt * a2[0]) * h0 + dx * Bv.x; acc  = h0 * Cv.x;
    h1 = exp2f(dlt * a2[1]) * h1 + dx * Bv.y; acc += h1 * Cv.y;
    h2 = exp2f(dlt * a2[2]) * h2 + dx * Bv.z; acc += h2 * Cv.z;
    h3 = exp2f(dlt * a2[3]) * h3 + dx * Bv.w; acc += h3 * Cv.w;
    acc += __shfl_xor(acc, 1);
    acc += __shfl_xor(acc, 2);
    if (ng == 0) {
      float zv = szo[t][dl];
      szo[t][dl] = (acc + xv * Dd) * (zv / (1.f + expf(-zv)));
    }
  }
  __syncthreads();
#pragma unroll
  for (int i = 0; i < 2; i++) {
    int f = tid + i * 256;
    int lr = f >> 4, c4 = (f & 15) * 4;
    float4 v = *(const float4*)&szo[lr][c4];
    bf16x4 h, l;
    hilo4(v, h, l);
    size_t o = (row0 + lr) * 2048 + d0 + c4;
    *(bf16x4*)&yh[o] = h;
    *(bf16x4*)&yl[o] = l;
  }
}

extern "C" void kernel_launch(void* const* d_in, const int* in_sizes, int n_in,
                              void* d_out, int out_size, void* d_ws, size_t ws_size,
                              hipStream_t stream)
{
  const float* hidden     = (const float*)d_in[0];
  const float* in_proj_w  = (const float*)d_in[1];
  const float* conv_w     = (const float*)d_in[2];
  const float* conv_b     = (const float*)d_in[3];
  const float* x_proj_w   = (const float*)d_in[4];
  const float* dt_proj_w  = (const float*)d_in[5];
  const float* A_log      = (const float*)d_in[6];
  const float* Dvec       = (const float*)d_in[7];
  const float* out_proj_w = (const float*)d_in[8];
  float* out = (float*)d_out;

  // ---- workspace arena (f32 element offsets); aliased regions noted ----
  float* w = (float*)d_ws;
  float* xz    = w;                         // 16,777,216   [gemm1 .. scan3]; later op_part (4 slabs)
  float* x     = xz + 16777216;             //  8,388,608   [conv .. scan3]
  float* x_dbl = x + 8388608;               //    393,216   [reduce_xp .. scan3]
  float* dreg  = x_dbl + 393216;            //  8,388,608   hid/inw cvt -> xh/xl -> delta
  float* Breg  = dreg + 8388608;            //  4,194,304   xp_part -> Bacc
  float* sdsum = Breg + 4194304;            //    262,144
  float* Dreg  = sdsum + 262144;            //  8,388,608   yh/yl
  float* wsm   = Dreg + 8388608;            //  2,752,512   small weights

  __bf16* d16   = (__bf16*)dreg;
  __bf16* hid_h = d16;                      // 4,194,304 bf16
  __bf16* hid_l = d16 + 4194304;
  __bf16* inw_h = d16 + 8388608;
  __bf16* inw_l = d16 + 12582912;
  __bf16* xh    = d16;                      // 8,388,608 bf16 (after gemm1)
  __bf16* xl    = d16 + 8388608;
  float*  delta = dreg;                     // f32 (after x_proj)
  float*  xp_part = Breg;                   // 8 x 524,288
  float*  Bacc    = Breg;                   // (after reduce_xproj)
  __bf16* yh = (__bf16*)Dreg;
  __bf16* yl = (__bf16*)Dreg + 8388608;
  float*  op_part = xz;                     // 4 x 4,194,304 (xz dead by then)

  __bf16* wm16  = (__bf16*)wsm;
  __bf16* xpw_h = wm16;                     // 128*2048 (rows 96..127 zero-padded)
  __bf16* xpw_l = wm16 + 262144;
  __bf16* dtw_h = wm16 + 524288;            // 2048*64
  __bf16* dtw_l = wm16 + 655360;
  __bf16* dth   = wm16 + 786432;            // 4096*64
  __bf16* dtl   = wm16 + 1048576;
  __bf16* ow_h  = wm16 + 1310720;           // 1024*2048
  __bf16* ow_l  = wm16 + 3407872;

  // ---- single fused conversion pass ----
  cvt_all<<<10624, 256, 0, stream>>>(hidden, in_proj_w, x_proj_w, dt_proj_w,
                                     out_proj_w, hid_h, hid_l, inw_h, inw_l,
                                     xpw_h, xpw_l, dtw_h, dtw_l, ow_h, ow_l);

  // xz = hidden @ in_proj_w^T   (M=4096, N=4096, K=1024) — 256x256 blocks
  gemm256<<<dim3(16, 16, 1), 512, 131072, stream>>>(hid_h, hid_l, inw_h, inw_l,
                                                    xz, 1024, 1024, 4096, 1024);
  // x = silu(conv(x_pre) + b), + hi/lo
  conv_silu_k<<<dim3(8, 4096), 256, 0, stream>>>(xz, conv_w, conv_b, x, xh, xl);
  // x_dbl partials = x @ x_proj_w^T  (split-K S=8, kseg=256, padded N=128)
  gemm3<<<dim3(1, 32, 8), 256, 0, stream>>>(xh, xl, xpw_h, xpw_l, xp_part,
                                            2048, 2048, 128, 256, 0);
  reduce_xproj<<<2048, 256, 0, stream>>>(xp_part, x_dbl, dth, dtl);
  // delta = softplus(dt @ dt_proj_w^T)  (K=64)
  gemm3<<<dim3(16, 32, 1), 256, 0, stream>>>(dth, dtl, dtw_h, dtw_l, delta,
                                             64, 64, 2048, 64, 1);
  // chunked selective scan (writes y as bf16 hi/lo)
  scan_chunk1<<<dim3(32, NCHK, 4), 256, 0, stream>>>(delta, x, x_dbl, A_log, Bacc, sdsum);
  scan_chunk2<<<128, 256, 0, stream>>>(A_log, sdsum, Bacc);
  scan_chunk3<<<dim3(32, NCHK, 4), 256, 0, stream>>>(delta, x, xz, x_dbl, A_log, Dvec,
                                                     Bacc, yh, yl);
  // out partials = y @ out_proj_w^T (256x256 blocks, split-K S=4, kseg=512)
  gemm256<<<dim3(4, 16, 4), 512, 131072, stream>>>(yh, yl, ow_h, ow_l, op_part,
                                                   2048, 2048, 1024, 512);
  reduce_oproj<<<4096, 256, 0, stream>>>(op_part, out);
}

// Round 9
// 355.399 us; speedup vs baseline: 1.0410x; 1.0410x over previous
//
#include <hip/hip_runtime.h>
#include <math.h>

// ---------------------------------------------------------------------------
// Mamba block forward. b=4, l=1024, dm=1024, di=2048, n=16, r=64.
// GEMMs: pure-bf16 MFMA (hi/lo split, 3 MFMA/product), inputs pre-converted.
// R9: gemm256 reverted to R7 (best measured; 2-barrier family ceiling).
//     conv_silu strip-tiled in LDS (kills 4x strided re-read of xz).
// Scan: chunked 3-phase (32 chunks x 32 steps).
// ---------------------------------------------------------------------------

typedef __bf16 bf16x8 __attribute__((ext_vector_type(8)));
typedef __bf16 bf16x4 __attribute__((ext_vector_type(4)));
typedef float f32x4 __attribute__((ext_vector_type(4)));

__device__ __forceinline__ void gload16(const void* g, void* lds_p) {
  __builtin_amdgcn_global_load_lds((const __attribute__((address_space(1))) void*)g,
                                   (__attribute__((address_space(3))) void*)lds_p,
                                   16, 0, 0);
}

// ---------------- f32 -> bf16 hi/lo conversion ----------------
__device__ __forceinline__ void hilo4(float4 v, bf16x4& h, bf16x4& l) {
  h[0] = (__bf16)v.x; l[0] = (__bf16)(v.x - (float)h[0]);
  h[1] = (__bf16)v.y; l[1] = (__bf16)(v.y - (float)h[1]);
  h[2] = (__bf16)v.z; l[2] = (__bf16)(v.z - (float)h[2]);
  h[3] = (__bf16)v.w; l[3] = (__bf16)(v.w - (float)h[3]);
}

// One fused conversion pass over all five f32 tensors + xpw zero-pad.
__global__ __launch_bounds__(256) void cvt_all(
    const float* __restrict__ hidden, const float* __restrict__ in_proj_w,
    const float* __restrict__ x_proj_w, const float* __restrict__ dt_proj_w,
    const float* __restrict__ out_proj_w,
    __bf16* __restrict__ hid_h, __bf16* __restrict__ hid_l,
    __bf16* __restrict__ inw_h, __bf16* __restrict__ inw_l,
    __bf16* __restrict__ xpw_h, __bf16* __restrict__ xpw_l,
    __bf16* __restrict__ dtw_h, __bf16* __restrict__ dtw_l,
    __bf16* __restrict__ ow_h,  __bf16* __restrict__ ow_l)
{
  int i = blockIdx.x * 256 + threadIdx.x;
  const float* s; __bf16 *H, *L; int off;
  if (i < 1048576)      { s = hidden;     H = hid_h; L = hid_l; off = i; }
  else if (i < 2097152) { s = in_proj_w;  H = inw_h; L = inw_l; off = i - 1048576; }
  else if (i < 2146304) { s = x_proj_w;   H = xpw_h; L = xpw_l; off = i - 2097152; }
  else if (i < 2179072) { s = dt_proj_w;  H = dtw_h; L = dtw_l; off = i - 2146304; }
  else if (i < 2703360) { s = out_proj_w; H = ow_h;  L = ow_l;  off = i - 2179072; }
  else {  // zero-pad xpw rows 96..127
    int j = i - 2703360;
    bf16x4 z = {};
    ((bf16x4*)(xpw_h + 196608))[j] = z;
    ((bf16x4*)(xpw_l + 196608))[j] = z;
    return;
  }
  float4 v = ((const float4*)s)[off];
  bf16x4 h, l;
  hilo4(v, h, l);
  ((bf16x4*)H)[off] = h;
  ((bf16x4*)L)[off] = l;
}

// ---------------------------------------------------------------------------
// Big NT GEMM: 256x256 block, 8 waves, wave tile 128x64 (acc 8x4 f32x4).
// R7 configuration (best measured: 99 us on in_proj).
// ---------------------------------------------------------------------------
__global__ __launch_bounds__(512, 1) void gemm256(
    const __bf16* __restrict__ Ah, const __bf16* __restrict__ Al,
    const __bf16* __restrict__ Bh, const __bf16* __restrict__ Bl,
    float* __restrict__ C, int lda, int ldb, int ldc, int kseg)
{
  extern __shared__ __align__(16) __bf16 lds[];   // 2 x 32768 elements

  const int tid = threadIdx.x;
  const int lane = tid & 63;
  const int laneL = lane & 15;
  const int laneH = lane >> 4;
  const int wave = tid >> 6;        // 0..7
  const int wm = wave >> 2;         // 0..1 (M half)
  const int wn = wave & 3;          // 0..3 (N quarter)

  // bijective XCD swizzle over the (x,y) grid plane
  const int nbx = gridDim.x;
  const int nwg = nbx * gridDim.y;
  int wg = blockIdx.y * nbx + blockIdx.x;
  wg = (wg & 7) * (nwg >> 3) + (wg >> 3);
  const int row0 = (wg / nbx) * 256;
  const int col0 = (wg % nbx) * 256;
  const int k0base = blockIdx.z * kseg;

  // staging role: wave -> (matrix, row-half)
  const int mat = wave >> 1;        // 0 Ah, 1 Al, 2 Bh, 3 Bl
  const int half = wave & 1;
  const __bf16* src = (mat == 0) ? Ah : (mat == 1) ? Al : (mat == 2) ? Bh : Bl;
  const int srcLd = (mat < 2) ? lda : ldb;
  const int srcRow0 = ((mat < 2) ? row0 : col0) + half * 128;
  const int lr = lane >> 2;          // 0..15
  const int ls = lane & 3;           // 0..3
  const int ksl = (ls ^ ((lr >> 1) & 3)) * 8;   // pre-swizzled k offset
  const __bf16* gbase = src + (size_t)(srcRow0 + lr) * srcLd + ksl;
  const int dstoff = mat * 8192 + half * 4096 + lane * 8;

  const int rsw = (laneL >> 1) & 3;  // read-side swizzle
  f32x4 acc[8][4] = {};
  const int nk = kseg >> 5;

  // prologue: stage tile 0 into buffer 0
  {
    const __bf16* g = gbase + k0base;
    __bf16* dst = lds + dstoff;
#pragma unroll
    for (int i = 0; i < 8; i++)
      gload16(g + (size_t)i * 16 * srcLd, dst + i * 512);
  }

  int cur = 0;
  for (int t = 0; t < nk; t++) {
    if (t + 1 < nk) {
      const __bf16* g = gbase + k0base + (t + 1) * 32;
      __bf16* dst = lds + (cur ^ 1) * 32768 + dstoff;
#pragma unroll
      for (int i = 0; i < 8; i++)
        gload16(g + (size_t)i * 16 * srcLd, dst + i * 512);
      asm volatile("s_waitcnt vmcnt(8)" ::: "memory");  // tile t complete
    } else {
      asm volatile("s_waitcnt vmcnt(0)" ::: "memory");
    }
    __builtin_amdgcn_s_barrier();
    __builtin_amdgcn_sched_barrier(0);

    const __bf16* base = lds + cur * 32768;
    const __bf16* sAh = base;
    const __bf16* sAl = base + 8192;
    const __bf16* sBh = base + 16384;
    const __bf16* sBl = base + 24576;

    bf16x8 bh[4], bl[4];
#pragma unroll
    for (int j = 0; j < 4; j++) {
      int off = (wn * 64 + j * 16 + laneL) * 32 + ((laneH ^ rsw) << 3);
      bh[j] = *(const bf16x8*)&sBh[off];
      bl[j] = *(const bf16x8*)&sBl[off];
    }
    __builtin_amdgcn_s_setprio(1);
#pragma unroll
    for (int i = 0; i < 8; i++) {
      int off = (wm * 128 + i * 16 + laneL) * 32 + ((laneH ^ rsw) << 3);
      bf16x8 ah = *(const bf16x8*)&sAh[off];
      bf16x8 al = *(const bf16x8*)&sAl[off];
#pragma unroll
      for (int j = 0; j < 4; j++) {
        acc[i][j] = __builtin_amdgcn_mfma_f32_16x16x32_bf16(ah, bh[j], acc[i][j], 0, 0, 0);
        acc[i][j] = __builtin_amdgcn_mfma_f32_16x16x32_bf16(ah, bl[j], acc[i][j], 0, 0, 0);
        acc[i][j] = __builtin_amdgcn_mfma_f32_16x16x32_bf16(al, bh[j], acc[i][j], 0, 0, 0);
      }
    }
    __builtin_amdgcn_s_setprio(0);
    __builtin_amdgcn_sched_barrier(0);
    __builtin_amdgcn_s_barrier();   // all reads done before re-stage
    cur ^= 1;
  }

  float* Cz = C + (size_t)blockIdx.z * gridDim.y * 256 * ldc;
#pragma unroll
  for (int i = 0; i < 8; i++) {
    int rr = row0 + wm * 128 + i * 16 + laneH * 4;
#pragma unroll
    for (int j = 0; j < 4; j++) {
      int cc = col0 + wn * 64 + j * 16 + laneL;
#pragma unroll
      for (int r = 0; r < 4; r++)
        Cz[(size_t)(rr + r) * ldc + cc] = acc[i][j][r];
    }
  }
}

// ---------------------------------------------------------------------------
// Small NT GEMM (128x128, 4 waves) for x_proj / dt_proj. Unchanged.
// ---------------------------------------------------------------------------
__global__ __launch_bounds__(256, 2) void gemm3(
    const __bf16* __restrict__ Ah, const __bf16* __restrict__ Al,
    const __bf16* __restrict__ Bh, const __bf16* __restrict__ Bl,
    float* __restrict__ C, int lda, int ldb, int ldc, int kseg, int epi)
{
  __shared__ __align__(16) __bf16 lds[2][4][128 * 32];

  const int tid = threadIdx.x;
  const int lane = tid & 63;
  const int laneL = lane & 15;
  const int laneH = lane >> 4;
  const int wave = tid >> 6;
  const int wm = wave >> 1;
  const int wn = wave & 1;
  const int row0 = blockIdx.y * 128;
  const int col0 = blockIdx.x * 128;
  const int k0base = blockIdx.z * kseg;

  const __bf16* src = (wave == 0) ? Ah : (wave == 1) ? Al : (wave == 2) ? Bh : Bl;
  const int srcLd = (wave < 2) ? lda : ldb;
  const int srcRow0 = (wave < 2) ? row0 : col0;
  const int lr = lane >> 2;
  const int ls = lane & 3;
  const int ksl = (ls ^ ((lr >> 1) & 3)) * 8;
  const __bf16* gbase = src + (size_t)(srcRow0 + lr) * srcLd + ksl;

  const int rsw = (laneL >> 1) & 3;
  f32x4 acc[4][4] = {};
  const int nk = kseg >> 5;

  {
    const __bf16* g = gbase + k0base;
    __bf16* dst = &lds[0][wave][lane * 8];
#pragma unroll
    for (int i = 0; i < 8; i++)
      gload16(g + (size_t)i * 16 * srcLd, dst + i * 512);
  }

  int cur = 0;
  for (int t = 0; t < nk; t++) {
    if (t + 1 < nk) {
      const __bf16* g = gbase + k0base + (t + 1) * 32;
      __bf16* dst = &lds[cur ^ 1][wave][lane * 8];
#pragma unroll
      for (int i = 0; i < 8; i++)
        gload16(g + (size_t)i * 16 * srcLd, dst + i * 512);
      asm volatile("s_waitcnt vmcnt(8)" ::: "memory");
    } else {
      asm volatile("s_waitcnt vmcnt(0)" ::: "memory");
    }
    __builtin_amdgcn_s_barrier();
    __builtin_amdgcn_sched_barrier(0);

    const __bf16* sAh = lds[cur][0];
    const __bf16* sAl = lds[cur][1];
    const __bf16* sBh = lds[cur][2];
    const __bf16* sBl = lds[cur][3];

    bf16x8 ah[4], al[4], bh[4], bl[4];
#pragma unroll
    for (int i = 0; i < 4; i++) {
      int off = (wm * 64 + i * 16 + laneL) * 32 + ((laneH ^ rsw) << 3);
      ah[i] = *(const bf16x8*)&sAh[off];
      al[i] = *(const bf16x8*)&sAl[off];
    }
#pragma unroll
    for (int j = 0; j < 4; j++) {
      int off = (wn * 64 + j * 16 + laneL) * 32 + ((laneH ^ rsw) << 3);
      bh[j] = *(const bf16x8*)&sBh[off];
      bl[j] = *(const bf16x8*)&sBl[off];
    }
#pragma unroll
    for (int i = 0; i < 4; i++)
#pragma unroll
      for (int j = 0; j < 4; j++) {
        acc[i][j] = __builtin_amdgcn_mfma_f32_16x16x32_bf16(ah[i], bh[j], acc[i][j], 0, 0, 0);
        acc[i][j] = __builtin_amdgcn_mfma_f32_16x16x32_bf16(ah[i], bl[j], acc[i][j], 0, 0, 0);
        acc[i][j] = __builtin_amdgcn_mfma_f32_16x16x32_bf16(al[i], bh[j], acc[i][j], 0, 0, 0);
      }
    __builtin_amdgcn_sched_barrier(0);
    __builtin_amdgcn_s_barrier();
    cur ^= 1;
  }

  float* Cz = C + (size_t)blockIdx.z * gridDim.y * 128 * ldc;
#pragma unroll
  for (int i = 0; i < 4; i++) {
    int rr = row0 + wm * 64 + i * 16 + laneH * 4;
#pragma unroll
    for (int j = 0; j < 4; j++) {
      int cc = col0 + wn * 64 + j * 16 + laneL;
#pragma unroll
      for (int r = 0; r < 4; r++) {
        float v = acc[i][j][r];
        if (epi == 1) v = (v > 20.f) ? v : log1pf(expf(v));
        Cz[(size_t)(rr + r) * ldc + cc] = v;
      }
    }
  }
}

// ---------------- split-K reduces ----------------
__global__ __launch_bounds__(256) void reduce_xproj(
    const float* __restrict__ part, float* __restrict__ x_dbl,
    __bf16* __restrict__ dth, __bf16* __restrict__ dtl)
{
  int idx = blockIdx.x * 256 + threadIdx.x;   // 0 .. 4096*128-1
  int row = idx >> 7, col = idx & 127;
  float v = 0.f;
#pragma unroll
  for (int s = 0; s < 8; s++) v += part[(size_t)s * 524288 + idx];
  if (col < 96) x_dbl[(size_t)row * 96 + col] = v;
  if (col < 64) {
    __bf16 h = (__bf16)v;
    dth[(size_t)row * 64 + col] = h;
    dtl[(size_t)row * 64 + col] = (__bf16)(v - (float)h);
  }
}

// out_proj: 4 partials (4096 x 1024), sum -> out.
__global__ __launch_bounds__(256) void reduce_oproj(
    const float* __restrict__ part, float* __restrict__ out)
{
  int i = blockIdx.x * 256 + threadIdx.x;     // 0 .. 1048575 float4 units
  const float4 a = ((const float4*)part)[i];
  const float4 b = ((const float4*)part)[i + 1048576];
  const float4 c = ((const float4*)part)[i + 2097152];
  const float4 d = ((const float4*)part)[i + 3145728];
  float4 o = make_float4(a.x + b.x + c.x + d.x, a.y + b.y + c.y + d.y,
                         a.z + b.z + c.z + d.z, a.w + b.w + c.w + d.w);
  ((float4*)out)[i] = o;
}

// ---------------------------------------------------------------------------
// Depthwise causal conv (K=4) + bias + silu, strip-tiled:
// block = 256 threads = 256 d-channels x 32 l-steps. Stages a 35x256 f32
// strip of xz in LDS once (reads xz exactly 35/32 x), computes from LDS.
// grid (2048/256, 1024/32, 4).
// ---------------------------------------------------------------------------
__global__ __launch_bounds__(256) void conv_silu_k(
    const float* __restrict__ xz, const float* __restrict__ conv_w,
    const float* __restrict__ conv_b, float* __restrict__ x,
    __bf16* __restrict__ xh, __bf16* __restrict__ xl)
{
  __shared__ __align__(16) float s[35][256];

  const int tid = threadIdx.x;
  const int d0 = blockIdx.x * 256;
  const int l0 = blockIdx.y * 32;
  const int b = blockIdx.z;
  const size_t brow = (size_t)b * 1024;

  // stage rows l0-3 .. l0+31 (35 rows x 256 f32 = 2240 float4 units)
  for (int u = tid; u < 2240; u += 256) {
    int r = u >> 6;              // 0..34
    int c4 = (u & 63) * 4;
    int gl = l0 - 3 + r;
    float4 v = make_float4(0.f, 0.f, 0.f, 0.f);
    if (gl >= 0)
      v = *(const float4*)&xz[(brow + gl) * 4096 + d0 + c4];
    *(float4*)&s[r][c4] = v;
  }
  __syncthreads();

  const int d = d0 + tid;
  const float4 w = ((const float4*)conv_w)[d];
  const float bias = conv_b[d];
#pragma unroll 4
  for (int lt = 0; lt < 32; lt++) {
    float acc = bias;
    acc = fmaf(s[lt][tid],     w.x, acc);
    acc = fmaf(s[lt + 1][tid], w.y, acc);
    acc = fmaf(s[lt + 2][tid], w.z, acc);
    acc = fmaf(s[lt + 3][tid], w.w, acc);
    float sv = acc / (1.f + expf(-acc));
    size_t o = (brow + l0 + lt) * 2048 + d;
    x[o] = sv;
    __bf16 h = (__bf16)sv;
    xh[o] = h;
    xl[o] = (__bf16)(sv - (float)h);
  }
}

// ---------------- chunked selective scan ----------------
#define NCHK 32
#define LC   32
#define DB   64
#define LOG2E 1.44269504f

__global__ __launch_bounds__(256) void scan_chunk1(
    const float* __restrict__ delta, const float* __restrict__ x,
    const float* __restrict__ x_dbl, const float* __restrict__ A_log,
    float* __restrict__ Bacc, float* __restrict__ sdsum)
{
  __shared__ __align__(16) float sdel[LC][DB];
  __shared__ __align__(16) float sx[LC][DB];
  __shared__ __align__(16) float sB[LC][16];

  const int tid = threadIdx.x;
  const int dl = tid >> 2;
  const int ng = tid & 3;
  const int d0 = blockIdx.x * DB;
  const int c = blockIdx.y, b = blockIdx.z;
  const int d = d0 + dl;
  const size_t row0 = (size_t)b * 1024 + c * LC;

  float a2[4];
#pragma unroll
  for (int i = 0; i < 4; i++) a2[i] = -expf(A_log[d * 16 + ng * 4 + i]) * LOG2E;

#pragma unroll
  for (int i = 0; i < 2; i++) {
    int f = tid + i * 256;
    int lr = f >> 4, c4 = (f & 15) * 4;
    size_t g = (row0 + lr) * 2048 + d0 + c4;
    *(float4*)&sdel[lr][c4] = *(const float4*)&delta[g];
    *(float4*)&sx[lr][c4]   = *(const float4*)&x[g];
  }
  if (tid < 128) {
    int lr = tid >> 2, n4 = (tid & 3) * 4;
    *(float4*)&sB[lr][n4] = *(const float4*)&x_dbl[(row0 + lr) * 96 + 64 + n4];
  }
  __syncthreads();

  float q0 = 0.f, q1 = 0.f, q2 = 0.f, q3 = 0.f, sd = 0.f;
#pragma unroll
  for (int t = 0; t < LC; t++) {
    float dlt = sdel[t][dl];
    float dx = dlt * sx[t][dl];
    const float4 Bv = *(const float4*)&sB[t][ng * 4];
    q0 = exp2f(dlt * a2[0]) * q0 + dx * Bv.x;
    q1 = exp2f(dlt * a2[1]) * q1 + dx * Bv.y;
    q2 = exp2f(dlt * a2[2]) * q2 + dx * Bv.z;
    q3 = exp2f(dlt * a2[3]) * q3 + dx * Bv.w;
    sd += dlt;
  }
  size_t o = ((size_t)(b * NCHK + c) * 2048 + d) * 16 + ng * 4;
  *(float4*)&Bacc[o] = make_float4(q0, q1, q2, q3);
  if (ng == 0) sdsum[(size_t)(b * NCHK + c) * 2048 + d] = sd;
}

__global__ __launch_bounds__(256) void scan_chunk2(
    const float* __restrict__ A_log, const float* __restrict__ sdsum,
    float* __restrict__ BaccH)
{
  const int g = blockIdx.x * 256 + threadIdx.x;
  const int ng = g & 3;
  const int d = (g >> 2) & 2047;
  const int b = g >> 13;
  float a2[4];
#pragma unroll
  for (int i = 0; i < 4; i++) a2[i] = -expf(A_log[d * 16 + ng * 4 + i]) * LOG2E;
  float h0 = 0.f, h1 = 0.f, h2 = 0.f, h3 = 0.f;
#pragma unroll 4
  for (int c = 0; c < NCHK; c++) {
    size_t o = ((size_t)(b * NCHK + c) * 2048 + d) * 16 + ng * 4;
    const float4 Q = *(const float4*)&BaccH[o];
    const float sd = sdsum[(size_t)(b * NCHK + c) * 2048 + d];
    *(float4*)&BaccH[o] = make_float4(h0, h1, h2, h3);
    h0 = exp2f(sd * a2[0]) * h0 + Q.x;
    h1 = exp2f(sd * a2[1]) * h1 + Q.y;
    h2 = exp2f(sd * a2[2]) * h2 + Q.z;
    h3 = exp2f(sd * a2[3]) * h3 + Q.w;
  }
}

__global__ __launch_bounds__(256) void scan_chunk3(
    const float* __restrict__ delta, const float* __restrict__ x,
    const float* __restrict__ xz, const float* __restrict__ x_dbl,
    const float* __restrict__ A_log, const float* __restrict__ Dvec,
    const float* __restrict__ Hstart,
    __bf16* __restrict__ yh, __bf16* __restrict__ yl)
{
  __shared__ __align__(16) float sdel[LC][DB];
  __shared__ __align__(16) float sx[LC][DB];
  __shared__ __align__(16) float szo[LC][DB];
  __shared__ __align__(16) float sB[LC][16];
  __shared__ __align__(16) float sC[LC][16];

  const int tid = threadIdx.x;
  const int dl = tid >> 2;
  const int ng = tid & 3;
  const int d0 = blockIdx.x * DB;
  const int c = blockIdx.y, b = blockIdx.z;
  const int d = d0 + dl;
  const size_t row0 = (size_t)b * 1024 + c * LC;

  float a2[4];
#pragma unroll
  for (int i = 0; i < 4; i++) a2[i] = -expf(A_log[d * 16 + ng * 4 + i]) * LOG2E;
  const float Dd = Dvec[d];

#pragma unroll
  for (int i = 0; i < 2; i++) {
    int f = tid + i * 256;
    int lr = f >> 4, c4 = (f & 15) * 4;
    size_t g = (row0 + lr) * 2048 + d0 + c4;
    *(float4*)&sdel[lr][c4] = *(const float4*)&delta[g];
    *(float4*)&sx[lr][c4]   = *(const float4*)&x[g];
    *(float4*)&szo[lr][c4]  = *(const float4*)&xz[(row0 + lr) * 4096 + 2048 + d0 + c4];
  }
  {
    int which = tid >> 7;
    int f = tid & 127;
    int lr = f >> 2, n4 = (f & 3) * 4;
    float4 v = *(const float4*)&x_dbl[(row0 + lr) * 96 + 64 + which * 16 + n4];
    if (which == 0) *(float4*)&sB[lr][n4] = v;
    else            *(float4*)&sC[lr][n4] = v;
  }
  __syncthreads();

  size_t ho = ((size_t)(b * NCHK + c) * 2048 + d) * 16 + ng * 4;
  const float4 hv = *(const float4*)&Hstart[ho];
  float h0 = hv.x, h1 = hv.y, h2 = hv.z, h3 = hv.w;

#pragma unroll
  for (int t = 0; t < LC; t++) {
    float dlt = sdel[t][dl];
    float xv = sx[t][dl];
    float dx = dlt * xv;
    const float4 Bv = *(const float4*)&sB[t][ng * 4];
    const float4 Cv = *(const float4*)&sC[t][ng * 4];
    float acc;
    h0 = exp2f(dlt * a2[0]) * h0 + dx * Bv.x; acc  = h0 * Cv.x;
    h1 = exp2f(dlt * a2[1]) * h1 + dx * Bv.y; acc += h1 * Cv.y;
    h2 = exp2f(dlt * a2[2]) * h2 + dx * Bv.z; acc += h2 * Cv.z;
    h3 = exp2f(dlt * a2[3]) * h3 + dx * Bv.w; acc += h3 * Cv.w;
    acc += __shfl_xor(acc, 1);
    acc += __shfl_xor(acc, 2);
    if (ng == 0) {
      float zv = szo[t][dl];
      szo[t][dl] = (acc + xv * Dd) * (zv / (1.f + expf(-zv)));
    }
  }
  __syncthreads();
#pragma unroll
  for (int i = 0; i < 2; i++) {
    int f = tid + i * 256;
    int lr = f >> 4, c4 = (f & 15) * 4;
    float4 v = *(const float4*)&szo[lr][c4];
    bf16x4 h, l;
    hilo4(v, h, l);
    size_t o = (row0 + lr) * 2048 + d0 + c4;
    *(bf16x4*)&yh[o] = h;
    *(bf16x4*)&yl[o] = l;
  }
}

extern "C" void kernel_launch(void* const* d_in, const int* in_sizes, int n_in,
                              void* d_out, int out_size, void* d_ws, size_t ws_size,
                              hipStream_t stream)
{
  const float* hidden     = (const float*)d_in[0];
  const float* in_proj_w  = (const float*)d_in[1];
  const float* conv_w     = (const float*)d_in[2];
  const float* conv_b     = (const float*)d_in[3];
  const float* x_proj_w   = (const float*)d_in[4];
  const float* dt_proj_w  = (const float*)d_in[5];
  const float* A_log      = (const float*)d_in[6];
  const float* Dvec       = (const float*)d_in[7];
  const float* out_proj_w = (const float*)d_in[8];
  float* out = (float*)d_out;

  // ---- workspace arena (f32 element offsets); aliased regions noted ----
  float* w = (float*)d_ws;
  float* xz    = w;                         // 16,777,216   [gemm1 .. scan3]; later op_part (4 slabs)
  float* x     = xz + 16777216;             //  8,388,608   [conv .. scan3]
  float* x_dbl = x + 8388608;               //    393,216   [reduce_xp .. scan3]
  float* dreg  = x_dbl + 393216;            //  8,388,608   hid/inw cvt -> xh/xl -> delta
  float* Breg  = dreg + 8388608;            //  4,194,304   xp_part -> Bacc
  float* sdsum = Breg + 4194304;            //    262,144
  float* Dreg  = sdsum + 262144;            //  8,388,608   yh/yl
  float* wsm   = Dreg + 8388608;            //  2,752,512   small weights

  __bf16* d16   = (__bf16*)dreg;
  __bf16* hid_h = d16;                      // 4,194,304 bf16
  __bf16* hid_l = d16 + 4194304;
  __bf16* inw_h = d16 + 8388608;
  __bf16* inw_l = d16 + 12582912;
  __bf16* xh    = d16;                      // 8,388,608 bf16 (after gemm1)
  __bf16* xl    = d16 + 8388608;
  float*  delta = dreg;                     // f32 (after x_proj)
  float*  xp_part = Breg;                   // 8 x 524,288
  float*  Bacc    = Breg;                   // (after reduce_xproj)
  __bf16* yh = (__bf16*)Dreg;
  __bf16* yl = (__bf16*)Dreg + 8388608;
  float*  op_part = xz;                     // 4 x 4,194,304 (xz dead by then)

  __bf16* wm16  = (__bf16*)wsm;
  __bf16* xpw_h = wm16;                     // 128*2048 (rows 96..127 zero-padded)
  __bf16* xpw_l = wm16 + 262144;
  __bf16* dtw_h = wm16 + 524288;            // 2048*64
  __bf16* dtw_l = wm16 + 655360;
  __bf16* dth   = wm16 + 786432;            // 4096*64
  __bf16* dtl   = wm16 + 1048576;
  __bf16* ow_h  = wm16 + 1310720;           // 1024*2048
  __bf16* ow_l  = wm16 + 3407872;

  // ---- single fused conversion pass ----
  cvt_all<<<10624, 256, 0, stream>>>(hidden, in_proj_w, x_proj_w, dt_proj_w,
                                     out_proj_w, hid_h, hid_l, inw_h, inw_l,
                                     xpw_h, xpw_l, dtw_h, dtw_l, ow_h, ow_l);

  // xz = hidden @ in_proj_w^T   (M=4096, N=4096, K=1024) — 256x256 blocks
  gemm256<<<dim3(16, 16, 1), 512, 131072, stream>>>(hid_h, hid_l, inw_h, inw_l,
                                                    xz, 1024, 1024, 4096, 1024);
  // x = silu(conv(x_pre) + b), + hi/lo  (strip-tiled)
  conv_silu_k<<<dim3(8, 32, 4), 256, 0, stream>>>(xz, conv_w, conv_b, x, xh, xl);
  // x_dbl partials = x @ x_proj_w^T  (split-K S=8, kseg=256, padded N=128)
  gemm3<<<dim3(1, 32, 8), 256, 0, stream>>>(xh, xl, xpw_h, xpw_l, xp_part,
                                            2048, 2048, 128, 256, 0);
  reduce_xproj<<<2048, 256, 0, stream>>>(xp_part, x_dbl, dth, dtl);
  // delta = softplus(dt @ dt_proj_w^T)  (K=64)
  gemm3<<<dim3(16, 32, 1), 256, 0, stream>>>(dth, dtl, dtw_h, dtw_l, delta,
                                             64, 64, 2048, 64, 1);
  // chunked selective scan (writes y as bf16 hi/lo)
  scan_chunk1<<<dim3(32, NCHK, 4), 256, 0, stream>>>(delta, x, x_dbl, A_log, Bacc, sdsum);
  scan_chunk2<<<128, 256, 0, stream>>>(A_log, sdsum, Bacc);
  scan_chunk3<<<dim3(32, NCHK, 4), 256, 0, stream>>>(delta, x, xz, x_dbl, A_log, Dvec,
                                                     Bacc, yh, yl);
  // out partials = y @ out_proj_w^T (256x256 blocks, split-K S=4, kseg=512)
  gemm256<<<dim3(4, 16, 4), 512, 131072, stream>>>(yh, yl, ow_h, ow_l, op_part,
                                                   2048, 2048, 1024, 512);
  reduce_oproj<<<4096, 256, 0, stream>>>(op_part, out);
}

// Round 10
// 331.110 us; speedup vs baseline: 1.1174x; 1.0734x over previous
//
#include <hip/hip_runtime.h>
#include <math.h>

// ---------------------------------------------------------------------------
// Mamba block forward. b=4, l=1024, dm=1024, di=2048, n=16, r=64.
// R10: GEMMs use the 2-MFMA mixed-precision scheme:
//   C ~= mfma_f16(A_f16, W_f16) + mfma_bf16(A_bf16, W_res_bf16)
//   where W_res = bf16(W - fp16(W)).  Dropped term A_res*W ~ 2^-12 rel.
//   (bf16 residual avoids fp16-denormal flush: |W_res| ~ 1e-6.)
// Activations: fp16 + bf16 copies. Weights: fp16 + bf16 residual.
// Scan: chunked 3-phase. Conv: strip-tiled LDS.
// ---------------------------------------------------------------------------

typedef __bf16 bf16x8 __attribute__((ext_vector_type(8)));
typedef __bf16 bf16x4 __attribute__((ext_vector_type(4)));
typedef _Float16 f16x8 __attribute__((ext_vector_type(8)));
typedef _Float16 f16x4 __attribute__((ext_vector_type(4)));
typedef float f32x4 __attribute__((ext_vector_type(4)));

__device__ __forceinline__ void gload16(const void* g, void* lds_p) {
  __builtin_amdgcn_global_load_lds((const __attribute__((address_space(1))) void*)g,
                                   (__attribute__((address_space(3))) void*)lds_p,
                                   16, 0, 0);
}

// activation: fp16 copy + bf16 copy
__device__ __forceinline__ void cvt_act4(float4 v, f16x4& f, bf16x4& b) {
  f[0] = (_Float16)v.x; b[0] = (__bf16)v.x;
  f[1] = (_Float16)v.y; b[1] = (__bf16)v.y;
  f[2] = (_Float16)v.z; b[2] = (__bf16)v.z;
  f[3] = (_Float16)v.w; b[3] = (__bf16)v.w;
}
// weight: fp16 main + bf16 residual
__device__ __forceinline__ void cvt_wgt4(float4 v, f16x4& f, bf16x4& r) {
  f[0] = (_Float16)v.x; r[0] = (__bf16)(v.x - (float)f[0]);
  f[1] = (_Float16)v.y; r[1] = (__bf16)(v.y - (float)f[1]);
  f[2] = (_Float16)v.z; r[2] = (__bf16)(v.z - (float)f[2]);
  f[3] = (_Float16)v.w; r[3] = (__bf16)(v.w - (float)f[3]);
}

// One fused conversion pass over all five f32 tensors + xpw zero-pad.
__global__ __launch_bounds__(256) void cvt_all(
    const float* __restrict__ hidden, const float* __restrict__ in_proj_w,
    const float* __restrict__ x_proj_w, const float* __restrict__ dt_proj_w,
    const float* __restrict__ out_proj_w,
    _Float16* __restrict__ hid_f, __bf16* __restrict__ hid_b,
    _Float16* __restrict__ inw_f, __bf16* __restrict__ inw_r,
    _Float16* __restrict__ xpw_f, __bf16* __restrict__ xpw_r,
    _Float16* __restrict__ dtw_f, __bf16* __restrict__ dtw_r,
    _Float16* __restrict__ ow_f,  __bf16* __restrict__ ow_r)
{
  int i = blockIdx.x * 256 + threadIdx.x;
  const float* s; _Float16* F; __bf16* R; int off; bool act = false;
  if (i < 1048576)      { s = hidden;     F = hid_f; R = hid_b; off = i; act = true; }
  else if (i < 2097152) { s = in_proj_w;  F = inw_f; R = inw_r; off = i - 1048576; }
  else if (i < 2146304) { s = x_proj_w;   F = xpw_f; R = xpw_r; off = i - 2097152; }
  else if (i < 2179072) { s = dt_proj_w;  F = dtw_f; R = dtw_r; off = i - 2146304; }
  else if (i < 2703360) { s = out_proj_w; F = ow_f;  R = ow_r;  off = i - 2179072; }
  else {  // zero-pad xpw rows 96..127
    int j = i - 2703360;
    f16x4 zf = {};
    bf16x4 zr = {};
    ((f16x4*)(xpw_f + 196608))[j] = zf;
    ((bf16x4*)(xpw_r + 196608))[j] = zr;
    return;
  }
  float4 v = ((const float4*)s)[off];
  f16x4 f; bf16x4 r;
  if (act) cvt_act4(v, f, r);
  else     cvt_wgt4(v, f, r);
  ((f16x4*)F)[off] = f;
  ((bf16x4*)R)[off] = r;
}

// ---------------------------------------------------------------------------
// Big NT GEMM: 256x256 block, 8 waves, wave tile 128x64 (acc 8x4 f32x4).
// Tiles: [0]=A_f16 [1]=A_bf16 [2]=B_f16 [3]=B_res_bf16. 2 MFMA per product.
// ---------------------------------------------------------------------------
__global__ __launch_bounds__(512, 1) void gemm256(
    const _Float16* __restrict__ Af, const __bf16* __restrict__ Ab,
    const _Float16* __restrict__ Bf, const __bf16* __restrict__ Br,
    float* __restrict__ C, int lda, int ldb, int ldc, int kseg)
{
  extern __shared__ __align__(16) __bf16 lds[];   // 2 x 32768 elements

  const int tid = threadIdx.x;
  const int lane = tid & 63;
  const int laneL = lane & 15;
  const int laneH = lane >> 4;
  const int wave = tid >> 6;        // 0..7
  const int wm = wave >> 2;         // 0..1 (M half)
  const int wn = wave & 3;          // 0..3 (N quarter)

  // bijective XCD swizzle over the (x,y) grid plane
  const int nbx = gridDim.x;
  const int nwg = nbx * gridDim.y;
  int wg = blockIdx.y * nbx + blockIdx.x;
  wg = (wg & 7) * (nwg >> 3) + (wg >> 3);
  const int row0 = (wg / nbx) * 256;
  const int col0 = (wg % nbx) * 256;
  const int k0base = blockIdx.z * kseg;

  // staging role: wave -> (matrix, row-half); all srcs are 2-byte elements
  const int mat = wave >> 1;        // 0 Af, 1 Ab, 2 Bf, 3 Br
  const int half = wave & 1;
  const __bf16* src = (mat == 0) ? (const __bf16*)Af : (mat == 1) ? Ab
                    : (mat == 2) ? (const __bf16*)Bf : Br;
  const int srcLd = (mat < 2) ? lda : ldb;
  const int srcRow0 = ((mat < 2) ? row0 : col0) + half * 128;
  const int lr = lane >> 2;          // 0..15
  const int ls = lane & 3;           // 0..3
  const int ksl = (ls ^ ((lr >> 1) & 3)) * 8;   // pre-swizzled k offset
  const __bf16* gbase = src + (size_t)(srcRow0 + lr) * srcLd + ksl;
  const int dstoff = mat * 8192 + half * 4096 + lane * 8;

  const int rsw = (laneL >> 1) & 3;  // read-side swizzle
  f32x4 acc[8][4] = {};
  const int nk = kseg >> 5;

  // prologue: stage tile 0 into buffer 0
  {
    const __bf16* g = gbase + k0base;
    __bf16* dst = lds + dstoff;
#pragma unroll
    for (int i = 0; i < 8; i++)
      gload16(g + (size_t)i * 16 * srcLd, dst + i * 512);
  }

  int cur = 0;
  for (int t = 0; t < nk; t++) {
    if (t + 1 < nk) {
      const __bf16* g = gbase + k0base + (t + 1) * 32;
      __bf16* dst = lds + (cur ^ 1) * 32768 + dstoff;
#pragma unroll
      for (int i = 0; i < 8; i++)
        gload16(g + (size_t)i * 16 * srcLd, dst + i * 512);
      asm volatile("s_waitcnt vmcnt(8)" ::: "memory");  // tile t complete
    } else {
      asm volatile("s_waitcnt vmcnt(0)" ::: "memory");
    }
    __builtin_amdgcn_s_barrier();
    __builtin_amdgcn_sched_barrier(0);

    const __bf16* base = lds + cur * 32768;
    const _Float16* sAf = (const _Float16*)base;
    const __bf16*   sAb = base + 8192;
    const _Float16* sBf = (const _Float16*)(base + 16384);
    const __bf16*   sBr = base + 24576;

    f16x8 bf[4]; bf16x8 br[4];
#pragma unroll
    for (int j = 0; j < 4; j++) {
      int off = (wn * 64 + j * 16 + laneL) * 32 + ((laneH ^ rsw) << 3);
      bf[j] = *(const f16x8*)&sBf[off];
      br[j] = *(const bf16x8*)&sBr[off];
    }
    __builtin_amdgcn_s_setprio(1);
#pragma unroll
    for (int i = 0; i < 8; i++) {
      int off = (wm * 128 + i * 16 + laneL) * 32 + ((laneH ^ rsw) << 3);
      f16x8  af = *(const f16x8*)&sAf[off];
      bf16x8 ab = *(const bf16x8*)&sAb[off];
#pragma unroll
      for (int j = 0; j < 4; j++) {
        acc[i][j] = __builtin_amdgcn_mfma_f32_16x16x32_f16(af, bf[j], acc[i][j], 0, 0, 0);
        acc[i][j] = __builtin_amdgcn_mfma_f32_16x16x32_bf16(ab, br[j], acc[i][j], 0, 0, 0);
      }
    }
    __builtin_amdgcn_s_setprio(0);
    __builtin_amdgcn_sched_barrier(0);
    __builtin_amdgcn_s_barrier();   // all reads done before re-stage
    cur ^= 1;
  }

  float* Cz = C + (size_t)blockIdx.z * gridDim.y * 256 * ldc;
#pragma unroll
  for (int i = 0; i < 8; i++) {
    int rr = row0 + wm * 128 + i * 16 + laneH * 4;
#pragma unroll
    for (int j = 0; j < 4; j++) {
      int cc = col0 + wn * 64 + j * 16 + laneL;
#pragma unroll
      for (int r = 0; r < 4; r++)
        Cz[(size_t)(rr + r) * ldc + cc] = acc[i][j][r];
    }
  }
}

// ---------------------------------------------------------------------------
// Small NT GEMM (128x128, 4 waves) for x_proj / dt_proj, same 2-MFMA scheme.
// ---------------------------------------------------------------------------
__global__ __launch_bounds__(256, 2) void gemm3(
    const _Float16* __restrict__ Af, const __bf16* __restrict__ Ab,
    const _Float16* __restrict__ Bf, const __bf16* __restrict__ Br,
    float* __restrict__ C, int lda, int ldb, int ldc, int kseg, int epi)
{
  __shared__ __align__(16) __bf16 lds[2][4][128 * 32];

  const int tid = threadIdx.x;
  const int lane = tid & 63;
  const int laneL = lane & 15;
  const int laneH = lane >> 4;
  const int wave = tid >> 6;
  const int wm = wave >> 1;
  const int wn = wave & 1;
  const int row0 = blockIdx.y * 128;
  const int col0 = blockIdx.x * 128;
  const int k0base = blockIdx.z * kseg;

  const __bf16* src = (wave == 0) ? (const __bf16*)Af : (wave == 1) ? Ab
                    : (wave == 2) ? (const __bf16*)Bf : Br;
  const int srcLd = (wave < 2) ? lda : ldb;
  const int srcRow0 = (wave < 2) ? row0 : col0;
  const int lr = lane >> 2;
  const int ls = lane & 3;
  const int ksl = (ls ^ ((lr >> 1) & 3)) * 8;
  const __bf16* gbase = src + (size_t)(srcRow0 + lr) * srcLd + ksl;

  const int rsw = (laneL >> 1) & 3;
  f32x4 acc[4][4] = {};
  const int nk = kseg >> 5;

  {
    const __bf16* g = gbase + k0base;
    __bf16* dst = &lds[0][wave][lane * 8];
#pragma unroll
    for (int i = 0; i < 8; i++)
      gload16(g + (size_t)i * 16 * srcLd, dst + i * 512);
  }

  int cur = 0;
  for (int t = 0; t < nk; t++) {
    if (t + 1 < nk) {
      const __bf16* g = gbase + k0base + (t + 1) * 32;
      __bf16* dst = &lds[cur ^ 1][wave][lane * 8];
#pragma unroll
      for (int i = 0; i < 8; i++)
        gload16(g + (size_t)i * 16 * srcLd, dst + i * 512);
      asm volatile("s_waitcnt vmcnt(8)" ::: "memory");
    } else {
      asm volatile("s_waitcnt vmcnt(0)" ::: "memory");
    }
    __builtin_amdgcn_s_barrier();
    __builtin_amdgcn_sched_barrier(0);

    const _Float16* sAf = (const _Float16*)lds[cur][0];
    const __bf16*   sAb = lds[cur][1];
    const _Float16* sBf = (const _Float16*)lds[cur][2];
    const __bf16*   sBr = lds[cur][3];

    f16x8 af[4], bf[4]; bf16x8 ab[4], br[4];
#pragma unroll
    for (int i = 0; i < 4; i++) {
      int off = (wm * 64 + i * 16 + laneL) * 32 + ((laneH ^ rsw) << 3);
      af[i] = *(const f16x8*)&sAf[off];
      ab[i] = *(const bf16x8*)&sAb[off];
    }
#pragma unroll
    for (int j = 0; j < 4; j++) {
      int off = (wn * 64 + j * 16 + laneL) * 32 + ((laneH ^ rsw) << 3);
      bf[j] = *(const f16x8*)&sBf[off];
      br[j] = *(const bf16x8*)&sBr[off];
    }
#pragma unroll
    for (int i = 0; i < 4; i++)
#pragma unroll
      for (int j = 0; j < 4; j++) {
        acc[i][j] = __builtin_amdgcn_mfma_f32_16x16x32_f16(af[i], bf[j], acc[i][j], 0, 0, 0);
        acc[i][j] = __builtin_amdgcn_mfma_f32_16x16x32_bf16(ab[i], br[j], acc[i][j], 0, 0, 0);
      }
    __builtin_amdgcn_sched_barrier(0);
    __builtin_amdgcn_s_barrier();
    cur ^= 1;
  }

  float* Cz = C + (size_t)blockIdx.z * gridDim.y * 128 * ldc;
#pragma unroll
  for (int i = 0; i < 4; i++) {
    int rr = row0 + wm * 64 + i * 16 + laneH * 4;
#pragma unroll
    for (int j = 0; j < 4; j++) {
      int cc = col0 + wn * 64 + j * 16 + laneL;
#pragma unroll
      for (int r = 0; r < 4; r++) {
        float v = acc[i][j][r];
        if (epi == 1) v = (v > 20.f) ? v : log1pf(expf(v));
        Cz[(size_t)(rr + r) * ldc + cc] = v;
      }
    }
  }
}

// ---------------- split-K reduces ----------------
__global__ __launch_bounds__(256) void reduce_xproj(
    const float* __restrict__ part, float* __restrict__ x_dbl,
    _Float16* __restrict__ dtf, __bf16* __restrict__ dtb)
{
  int idx = blockIdx.x * 256 + threadIdx.x;   // 0 .. 4096*128-1
  int row = idx >> 7, col = idx & 127;
  float v = 0.f;
#pragma unroll
  for (int s = 0; s < 8; s++) v += part[(size_t)s * 524288 + idx];
  if (col < 96) x_dbl[(size_t)row * 96 + col] = v;
  if (col < 64) {
    dtf[(size_t)row * 64 + col] = (_Float16)v;
    dtb[(size_t)row * 64 + col] = (__bf16)v;
  }
}

// out_proj: 4 partials (4096 x 1024), sum -> out.
__global__ __launch_bounds__(256) void reduce_oproj(
    const float* __restrict__ part, float* __restrict__ out)
{
  int i = blockIdx.x * 256 + threadIdx.x;     // 0 .. 1048575 float4 units
  const float4 a = ((const float4*)part)[i];
  const float4 b = ((const float4*)part)[i + 1048576];
  const float4 c = ((const float4*)part)[i + 2097152];
  const float4 d = ((const float4*)part)[i + 3145728];
  float4 o = make_float4(a.x + b.x + c.x + d.x, a.y + b.y + c.y + d.y,
                         a.z + b.z + c.z + d.z, a.w + b.w + c.w + d.w);
  ((float4*)out)[i] = o;
}

// ---------------------------------------------------------------------------
// Depthwise causal conv (K=4) + bias + silu, strip-tiled (R9).
// ---------------------------------------------------------------------------
__global__ __launch_bounds__(256) void conv_silu_k(
    const float* __restrict__ xz, const float* __restrict__ conv_w,
    const float* __restrict__ conv_b, float* __restrict__ x,
    _Float16* __restrict__ xf, __bf16* __restrict__ xb)
{
  __shared__ __align__(16) float s[35][256];

  const int tid = threadIdx.x;
  const int d0 = blockIdx.x * 256;
  const int l0 = blockIdx.y * 32;
  const int b = blockIdx.z;
  const size_t brow = (size_t)b * 1024;

  for (int u = tid; u < 2240; u += 256) {
    int r = u >> 6;
    int c4 = (u & 63) * 4;
    int gl = l0 - 3 + r;
    float4 v = make_float4(0.f, 0.f, 0.f, 0.f);
    if (gl >= 0)
      v = *(const float4*)&xz[(brow + gl) * 4096 + d0 + c4];
    *(float4*)&s[r][c4] = v;
  }
  __syncthreads();

  const int d = d0 + tid;
  const float4 w = ((const float4*)conv_w)[d];
  const float bias = conv_b[d];
#pragma unroll 4
  for (int lt = 0; lt < 32; lt++) {
    float acc = bias;
    acc = fmaf(s[lt][tid],     w.x, acc);
    acc = fmaf(s[lt + 1][tid], w.y, acc);
    acc = fmaf(s[lt + 2][tid], w.z, acc);
    acc = fmaf(s[lt + 3][tid], w.w, acc);
    float sv = acc / (1.f + expf(-acc));
    size_t o = (brow + l0 + lt) * 2048 + d;
    x[o] = sv;
    xf[o] = (_Float16)sv;
    xb[o] = (__bf16)sv;
  }
}

// ---------------- chunked selective scan ----------------
#define NCHK 32
#define LC   32
#define DB   64
#define LOG2E 1.44269504f

__global__ __launch_bounds__(256) void scan_chunk1(
    const float* __restrict__ delta, const float* __restrict__ x,
    const float* __restrict__ x_dbl, const float* __restrict__ A_log,
    float* __restrict__ Bacc, float* __restrict__ sdsum)
{
  __shared__ __align__(16) float sdel[LC][DB];
  __shared__ __align__(16) float sx[LC][DB];
  __shared__ __align__(16) float sB[LC][16];

  const int tid = threadIdx.x;
  const int dl = tid >> 2;
  const int ng = tid & 3;
  const int d0 = blockIdx.x * DB;
  const int c = blockIdx.y, b = blockIdx.z;
  const int d = d0 + dl;
  const size_t row0 = (size_t)b * 1024 + c * LC;

  float a2[4];
#pragma unroll
  for (int i = 0; i < 4; i++) a2[i] = -expf(A_log[d * 16 + ng * 4 + i]) * LOG2E;

#pragma unroll
  for (int i = 0; i < 2; i++) {
    int f = tid + i * 256;
    int lr = f >> 4, c4 = (f & 15) * 4;
    size_t g = (row0 + lr) * 2048 + d0 + c4;
    *(float4*)&sdel[lr][c4] = *(const float4*)&delta[g];
    *(float4*)&sx[lr][c4]   = *(const float4*)&x[g];
  }
  if (tid < 128) {
    int lr = tid >> 2, n4 = (tid & 3) * 4;
    *(float4*)&sB[lr][n4] = *(const float4*)&x_dbl[(row0 + lr) * 96 + 64 + n4];
  }
  __syncthreads();

  float q0 = 0.f, q1 = 0.f, q2 = 0.f, q3 = 0.f, sd = 0.f;
#pragma unroll
  for (int t = 0; t < LC; t++) {
    float dlt = sdel[t][dl];
    float dx = dlt * sx[t][dl];
    const float4 Bv = *(const float4*)&sB[t][ng * 4];
    q0 = exp2f(dlt * a2[0]) * q0 + dx * Bv.x;
    q1 = exp2f(dlt * a2[1]) * q1 + dx * Bv.y;
    q2 = exp2f(dlt * a2[2]) * q2 + dx * Bv.z;
    q3 = exp2f(dlt * a2[3]) * q3 + dx * Bv.w;
    sd += dlt;
  }
  size_t o = ((size_t)(b * NCHK + c) * 2048 + d) * 16 + ng * 4;
  *(float4*)&Bacc[o] = make_float4(q0, q1, q2, q3);
  if (ng == 0) sdsum[(size_t)(b * NCHK + c) * 2048 + d] = sd;
}

__global__ __launch_bounds__(256) void scan_chunk2(
    const float* __restrict__ A_log, const float* __restrict__ sdsum,
    float* __restrict__ BaccH)
{
  const int g = blockIdx.x * 256 + threadIdx.x;
  const int ng = g & 3;
  const int d = (g >> 2) & 2047;
  const int b = g >> 13;
  float a2[4];
#pragma unroll
  for (int i = 0; i < 4; i++) a2[i] = -expf(A_log[d * 16 + ng * 4 + i]) * LOG2E;
  float h0 = 0.f, h1 = 0.f, h2 = 0.f, h3 = 0.f;
#pragma unroll 4
  for (int c = 0; c < NCHK; c++) {
    size_t o = ((size_t)(b * NCHK + c) * 2048 + d) * 16 + ng * 4;
    const float4 Q = *(const float4*)&BaccH[o];
    const float sd = sdsum[(size_t)(b * NCHK + c) * 2048 + d];
    *(float4*)&BaccH[o] = make_float4(h0, h1, h2, h3);
    h0 = exp2f(sd * a2[0]) * h0 + Q.x;
    h1 = exp2f(sd * a2[1]) * h1 + Q.y;
    h2 = exp2f(sd * a2[2]) * h2 + Q.z;
    h3 = exp2f(sd * a2[3]) * h3 + Q.w;
  }
}

__global__ __launch_bounds__(256) void scan_chunk3(
    const float* __restrict__ delta, const float* __restrict__ x,
    const float* __restrict__ xz, const float* __restrict__ x_dbl,
    const float* __restrict__ A_log, const float* __restrict__ Dvec,
    const float* __restrict__ Hstart,
    _Float16* __restrict__ yf, __bf16* __restrict__ yb)
{
  __shared__ __align__(16) float sdel[LC][DB];
  __shared__ __align__(16) float sx[LC][DB];
  __shared__ __align__(16) float szo[LC][DB];
  __shared__ __align__(16) float sB[LC][16];
  __shared__ __align__(16) float sC[LC][16];

  const int tid = threadIdx.x;
  const int dl = tid >> 2;
  const int ng = tid & 3;
  const int d0 = blockIdx.x * DB;
  const int c = blockIdx.y, b = blockIdx.z;
  const int d = d0 + dl;
  const size_t row0 = (size_t)b * 1024 + c * LC;

  float a2[4];
#pragma unroll
  for (int i = 0; i < 4; i++) a2[i] = -expf(A_log[d * 16 + ng * 4 + i]) * LOG2E;
  const float Dd = Dvec[d];

#pragma unroll
  for (int i = 0; i < 2; i++) {
    int f = tid + i * 256;
    int lr = f >> 4, c4 = (f & 15) * 4;
    size_t g = (row0 + lr) * 2048 + d0 + c4;
    *(float4*)&sdel[lr][c4] = *(const float4*)&delta[g];
    *(float4*)&sx[lr][c4]   = *(const float4*)&x[g];
    *(float4*)&szo[lr][c4]  = *(const float4*)&xz[(row0 + lr) * 4096 + 2048 + d0 + c4];
  }
  {
    int which = tid >> 7;
    int f = tid & 127;
    int lr = f >> 2, n4 = (f & 3) * 4;
    float4 v = *(const float4*)&x_dbl[(row0 + lr) * 96 + 64 + which * 16 + n4];
    if (which == 0) *(float4*)&sB[lr][n4] = v;
    else            *(float4*)&sC[lr][n4] = v;
  }
  __syncthreads();

  size_t ho = ((size_t)(b * NCHK + c) * 2048 + d) * 16 + ng * 4;
  const float4 hv = *(const float4*)&Hstart[ho];
  float h0 = hv.x, h1 = hv.y, h2 = hv.z, h3 = hv.w;

#pragma unroll
  for (int t = 0; t < LC; t++) {
    float dlt = sdel[t][dl];
    float xv = sx[t][dl];
    float dx = dlt * xv;
    const float4 Bv = *(const float4*)&sB[t][ng * 4];
    const float4 Cv = *(const float4*)&sC[t][ng * 4];
    float acc;
    h0 = exp2f(dlt * a2[0]) * h0 + dx * Bv.x; acc  = h0 * Cv.x;
    h1 = exp2f(dlt * a2[1]) * h1 + dx * Bv.y; acc += h1 * Cv.y;
    h2 = exp2f(dlt * a2[2]) * h2 + dx * Bv.z; acc += h2 * Cv.z;
    h3 = exp2f(dlt * a2[3]) * h3 + dx * Bv.w; acc += h3 * Cv.w;
    acc += __shfl_xor(acc, 1);
    acc += __shfl_xor(acc, 2);
    if (ng == 0) {
      float zv = szo[t][dl];
      szo[t][dl] = (acc + xv * Dd) * (zv / (1.f + expf(-zv)));
    }
  }
  __syncthreads();
#pragma unroll
  for (int i = 0; i < 2; i++) {
    int f = tid + i * 256;
    int lr = f >> 4, c4 = (f & 15) * 4;
    float4 v = *(const float4*)&szo[lr][c4];
    f16x4 vf; bf16x4 vb;
    cvt_act4(v, vf, vb);
    size_t o = (row0 + lr) * 2048 + d0 + c4;
    *(f16x4*)&yf[o] = vf;
    *(bf16x4*)&yb[o] = vb;
  }
}

extern "C" void kernel_launch(void* const* d_in, const int* in_sizes, int n_in,
                              void* d_out, int out_size, void* d_ws, size_t ws_size,
                              hipStream_t stream)
{
  const float* hidden     = (const float*)d_in[0];
  const float* in_proj_w  = (const float*)d_in[1];
  const float* conv_w     = (const float*)d_in[2];
  const float* conv_b     = (const float*)d_in[3];
  const float* x_proj_w   = (const float*)d_in[4];
  const float* dt_proj_w  = (const float*)d_in[5];
  const float* A_log      = (const float*)d_in[6];
  const float* Dvec       = (const float*)d_in[7];
  const float* out_proj_w = (const float*)d_in[8];
  float* out = (float*)d_out;

  // ---- workspace arena (f32 element offsets); aliased regions noted ----
  float* w = (float*)d_ws;
  float* xz    = w;                         // 16,777,216   [gemm1 .. scan3]; later op_part
  float* x     = xz + 16777216;             //  8,388,608
  float* x_dbl = x + 8388608;               //    393,216
  float* dreg  = x_dbl + 393216;            //  8,388,608   hid/inw cvt -> xf/xb -> delta
  float* Breg  = dreg + 8388608;            //  4,194,304   xp_part -> Bacc
  float* sdsum = Breg + 4194304;            //    262,144
  float* Dreg  = sdsum + 262144;            //  8,388,608   yf/yb
  float* wsm   = Dreg + 8388608;            //  2,752,512   small weights

  __bf16* d16 = (__bf16*)dreg;
  _Float16* hid_f = (_Float16*)d16;              // 4,194,304 elems
  __bf16*   hid_b = d16 + 4194304;
  _Float16* inw_f = (_Float16*)(d16 + 8388608);
  __bf16*   inw_r = d16 + 12582912;
  _Float16* xf    = (_Float16*)d16;              // after gemm1 (hid/inw dead)
  __bf16*   xb    = d16 + 8388608;
  float*  delta   = dreg;                        // f32 (after x_proj)
  float*  xp_part = Breg;                        // 8 x 524,288
  float*  Bacc    = Breg;                        // (after reduce_xproj)
  _Float16* yf = (_Float16*)Dreg;
  __bf16*   yb = (__bf16*)Dreg + 8388608;
  float*  op_part = xz;                          // 4 x 4,194,304 (xz dead by then)

  __bf16* wm16 = (__bf16*)wsm;
  _Float16* xpw_f = (_Float16*)wm16;             // 128*2048 (rows 96..127 zero)
  __bf16*   xpw_r = wm16 + 262144;
  _Float16* dtw_f = (_Float16*)(wm16 + 524288);  // 2048*64
  __bf16*   dtw_r = wm16 + 655360;
  _Float16* dtf   = (_Float16*)(wm16 + 786432);  // 4096*64
  __bf16*   dtb   = wm16 + 1048576;
  _Float16* ow_f  = (_Float16*)(wm16 + 1310720); // 1024*2048
  __bf16*   ow_r  = wm16 + 3407872;

  // ---- single fused conversion pass ----
  cvt_all<<<10624, 256, 0, stream>>>(hidden, in_proj_w, x_proj_w, dt_proj_w,
                                     out_proj_w, hid_f, hid_b, inw_f, inw_r,
                                     xpw_f, xpw_r, dtw_f, dtw_r, ow_f, ow_r);

  // xz = hidden @ in_proj_w^T   (M=4096, N=4096, K=1024) — 256x256 blocks
  gemm256<<<dim3(16, 16, 1), 512, 131072, stream>>>(hid_f, hid_b, inw_f, inw_r,
                                                    xz, 1024, 1024, 4096, 1024);
  // x = silu(conv(x_pre) + b), + fp16/bf16 copies (strip-tiled)
  conv_silu_k<<<dim3(8, 32, 4), 256, 0, stream>>>(xz, conv_w, conv_b, x, xf, xb);
  // x_dbl partials = x @ x_proj_w^T  (split-K S=8, kseg=256, padded N=128)
  gemm3<<<dim3(1, 32, 8), 256, 0, stream>>>(xf, xb, xpw_f, xpw_r, xp_part,
                                            2048, 2048, 128, 256, 0);
  reduce_xproj<<<2048, 256, 0, stream>>>(xp_part, x_dbl, dtf, dtb);
  // delta = softplus(dt @ dt_proj_w^T)  (K=64)
  gemm3<<<dim3(16, 32, 1), 256, 0, stream>>>(dtf, dtb, dtw_f, dtw_r, delta,
                                             64, 64, 2048, 64, 1);
  // chunked selective scan (writes y as fp16 + bf16)
  scan_chunk1<<<dim3(32, NCHK, 4), 256, 0, stream>>>(delta, x, x_dbl, A_log, Bacc, sdsum);
  scan_chunk2<<<128, 256, 0, stream>>>(A_log, sdsum, Bacc);
  scan_chunk3<<<dim3(32, NCHK, 4), 256, 0, stream>>>(delta, x, xz, x_dbl, A_log, Dvec,
                                                     Bacc, yf, yb);
  // out partials = y @ out_proj_w^T (256x256 blocks, split-K S=4, kseg=512)
  gemm256<<<dim3(4, 16, 4), 512, 131072, stream>>>(yf, yb, ow_f, ow_r, op_part,
                                                   2048, 2048, 1024, 512);
  reduce_oproj<<<4096, 256, 0, stream>>>(op_part, out);
}

// Round 11
// 326.713 us; speedup vs baseline: 1.1325x; 1.0135x over previous
//
#include <hip/hip_runtime.h>
#include <math.h>

// ---------------------------------------------------------------------------
// Mamba block forward. b=4, l=1024, dm=1024, di=2048, n=16, r=64.
// GEMM scheme (R10): C ~= mfma_f16(A_f16,W_f16) + mfma_bf16(A_bf16,W_res).
// R11: out_proj moved to gemm3 128^2 S=1 writing d_out directly
//      (kills 64MB partial write + 12us reduce; 4x k-step amortization).
// Scan: chunked 3-phase. Conv: strip-tiled LDS.
// ---------------------------------------------------------------------------

typedef __bf16 bf16x8 __attribute__((ext_vector_type(8)));
typedef __bf16 bf16x4 __attribute__((ext_vector_type(4)));
typedef _Float16 f16x8 __attribute__((ext_vector_type(8)));
typedef _Float16 f16x4 __attribute__((ext_vector_type(4)));
typedef float f32x4 __attribute__((ext_vector_type(4)));

__device__ __forceinline__ void gload16(const void* g, void* lds_p) {
  __builtin_amdgcn_global_load_lds((const __attribute__((address_space(1))) void*)g,
                                   (__attribute__((address_space(3))) void*)lds_p,
                                   16, 0, 0);
}

// activation: fp16 copy + bf16 copy
__device__ __forceinline__ void cvt_act4(float4 v, f16x4& f, bf16x4& b) {
  f[0] = (_Float16)v.x; b[0] = (__bf16)v.x;
  f[1] = (_Float16)v.y; b[1] = (__bf16)v.y;
  f[2] = (_Float16)v.z; b[2] = (__bf16)v.z;
  f[3] = (_Float16)v.w; b[3] = (__bf16)v.w;
}
// weight: fp16 main + bf16 residual
__device__ __forceinline__ void cvt_wgt4(float4 v, f16x4& f, bf16x4& r) {
  f[0] = (_Float16)v.x; r[0] = (__bf16)(v.x - (float)f[0]);
  f[1] = (_Float16)v.y; r[1] = (__bf16)(v.y - (float)f[1]);
  f[2] = (_Float16)v.z; r[2] = (__bf16)(v.z - (float)f[2]);
  f[3] = (_Float16)v.w; r[3] = (__bf16)(v.w - (float)f[3]);
}

// One fused conversion pass over all five f32 tensors + xpw zero-pad.
__global__ __launch_bounds__(256) void cvt_all(
    const float* __restrict__ hidden, const float* __restrict__ in_proj_w,
    const float* __restrict__ x_proj_w, const float* __restrict__ dt_proj_w,
    const float* __restrict__ out_proj_w,
    _Float16* __restrict__ hid_f, __bf16* __restrict__ hid_b,
    _Float16* __restrict__ inw_f, __bf16* __restrict__ inw_r,
    _Float16* __restrict__ xpw_f, __bf16* __restrict__ xpw_r,
    _Float16* __restrict__ dtw_f, __bf16* __restrict__ dtw_r,
    _Float16* __restrict__ ow_f,  __bf16* __restrict__ ow_r)
{
  int i = blockIdx.x * 256 + threadIdx.x;
  const float* s; _Float16* F; __bf16* R; int off; bool act = false;
  if (i < 1048576)      { s = hidden;     F = hid_f; R = hid_b; off = i; act = true; }
  else if (i < 2097152) { s = in_proj_w;  F = inw_f; R = inw_r; off = i - 1048576; }
  else if (i < 2146304) { s = x_proj_w;   F = xpw_f; R = xpw_r; off = i - 2097152; }
  else if (i < 2179072) { s = dt_proj_w;  F = dtw_f; R = dtw_r; off = i - 2146304; }
  else if (i < 2703360) { s = out_proj_w; F = ow_f;  R = ow_r;  off = i - 2179072; }
  else {  // zero-pad xpw rows 96..127
    int j = i - 2703360;
    f16x4 zf = {};
    bf16x4 zr = {};
    ((f16x4*)(xpw_f + 196608))[j] = zf;
    ((bf16x4*)(xpw_r + 196608))[j] = zr;
    return;
  }
  float4 v = ((const float4*)s)[off];
  f16x4 f; bf16x4 r;
  if (act) cvt_act4(v, f, r);
  else     cvt_wgt4(v, f, r);
  ((f16x4*)F)[off] = f;
  ((bf16x4*)R)[off] = r;
}

// ---------------------------------------------------------------------------
// Big NT GEMM: 256x256 block, 8 waves, wave tile 128x64 (acc 8x4 f32x4).
// Tiles: [0]=A_f16 [1]=A_bf16 [2]=B_f16 [3]=B_res_bf16. 2 MFMA per product.
// Used for in_proj only.
// ---------------------------------------------------------------------------
__global__ __launch_bounds__(512, 1) void gemm256(
    const _Float16* __restrict__ Af, const __bf16* __restrict__ Ab,
    const _Float16* __restrict__ Bf, const __bf16* __restrict__ Br,
    float* __restrict__ C, int lda, int ldb, int ldc, int kseg)
{
  extern __shared__ __align__(16) __bf16 lds[];   // 2 x 32768 elements

  const int tid = threadIdx.x;
  const int lane = tid & 63;
  const int laneL = lane & 15;
  const int laneH = lane >> 4;
  const int wave = tid >> 6;        // 0..7
  const int wm = wave >> 2;         // 0..1 (M half)
  const int wn = wave & 3;          // 0..3 (N quarter)

  // bijective XCD swizzle over the (x,y) grid plane
  const int nbx = gridDim.x;
  const int nwg = nbx * gridDim.y;
  int wg = blockIdx.y * nbx + blockIdx.x;
  wg = (wg & 7) * (nwg >> 3) + (wg >> 3);
  const int row0 = (wg / nbx) * 256;
  const int col0 = (wg % nbx) * 256;
  const int k0base = blockIdx.z * kseg;

  // staging role: wave -> (matrix, row-half); all srcs are 2-byte elements
  const int mat = wave >> 1;        // 0 Af, 1 Ab, 2 Bf, 3 Br
  const int half = wave & 1;
  const __bf16* src = (mat == 0) ? (const __bf16*)Af : (mat == 1) ? Ab
                    : (mat == 2) ? (const __bf16*)Bf : Br;
  const int srcLd = (mat < 2) ? lda : ldb;
  const int srcRow0 = ((mat < 2) ? row0 : col0) + half * 128;
  const int lr = lane >> 2;          // 0..15
  const int ls = lane & 3;           // 0..3
  const int ksl = (ls ^ ((lr >> 1) & 3)) * 8;   // pre-swizzled k offset
  const __bf16* gbase = src + (size_t)(srcRow0 + lr) * srcLd + ksl;
  const int dstoff = mat * 8192 + half * 4096 + lane * 8;

  const int rsw = (laneL >> 1) & 3;  // read-side swizzle
  f32x4 acc[8][4] = {};
  const int nk = kseg >> 5;

  // prologue: stage tile 0 into buffer 0
  {
    const __bf16* g = gbase + k0base;
    __bf16* dst = lds + dstoff;
#pragma unroll
    for (int i = 0; i < 8; i++)
      gload16(g + (size_t)i * 16 * srcLd, dst + i * 512);
  }

  int cur = 0;
  for (int t = 0; t < nk; t++) {
    if (t + 1 < nk) {
      const __bf16* g = gbase + k0base + (t + 1) * 32;
      __bf16* dst = lds + (cur ^ 1) * 32768 + dstoff;
#pragma unroll
      for (int i = 0; i < 8; i++)
        gload16(g + (size_t)i * 16 * srcLd, dst + i * 512);
      asm volatile("s_waitcnt vmcnt(8)" ::: "memory");  // tile t complete
    } else {
      asm volatile("s_waitcnt vmcnt(0)" ::: "memory");
    }
    __builtin_amdgcn_s_barrier();
    __builtin_amdgcn_sched_barrier(0);

    const __bf16* base = lds + cur * 32768;
    const _Float16* sAf = (const _Float16*)base;
    const __bf16*   sAb = base + 8192;
    const _Float16* sBf = (const _Float16*)(base + 16384);
    const __bf16*   sBr = base + 24576;

    f16x8 bf[4]; bf16x8 br[4];
#pragma unroll
    for (int j = 0; j < 4; j++) {
      int off = (wn * 64 + j * 16 + laneL) * 32 + ((laneH ^ rsw) << 3);
      bf[j] = *(const f16x8*)&sBf[off];
      br[j] = *(const bf16x8*)&sBr[off];
    }
    __builtin_amdgcn_s_setprio(1);
#pragma unroll
    for (int i = 0; i < 8; i++) {
      int off = (wm * 128 + i * 16 + laneL) * 32 + ((laneH ^ rsw) << 3);
      f16x8  af = *(const f16x8*)&sAf[off];
      bf16x8 ab = *(const bf16x8*)&sAb[off];
#pragma unroll
      for (int j = 0; j < 4; j++) {
        acc[i][j] = __builtin_amdgcn_mfma_f32_16x16x32_f16(af, bf[j], acc[i][j], 0, 0, 0);
        acc[i][j] = __builtin_amdgcn_mfma_f32_16x16x32_bf16(ab, br[j], acc[i][j], 0, 0, 0);
      }
    }
    __builtin_amdgcn_s_setprio(0);
    __builtin_amdgcn_sched_barrier(0);
    __builtin_amdgcn_s_barrier();   // all reads done before re-stage
    cur ^= 1;
  }

  float* Cz = C + (size_t)blockIdx.z * gridDim.y * 256 * ldc;
#pragma unroll
  for (int i = 0; i < 8; i++) {
    int rr = row0 + wm * 128 + i * 16 + laneH * 4;
#pragma unroll
    for (int j = 0; j < 4; j++) {
      int cc = col0 + wn * 64 + j * 16 + laneL;
#pragma unroll
      for (int r = 0; r < 4; r++)
        Cz[(size_t)(rr + r) * ldc + cc] = acc[i][j][r];
    }
  }
}

// ---------------------------------------------------------------------------
// Small NT GEMM (128x128, 4 waves), 2-MFMA scheme.
// Used for x_proj (split-K slabs), dt_proj, and out_proj (S=1 direct write).
// ---------------------------------------------------------------------------
__global__ __launch_bounds__(256, 2) void gemm3(
    const _Float16* __restrict__ Af, const __bf16* __restrict__ Ab,
    const _Float16* __restrict__ Bf, const __bf16* __restrict__ Br,
    float* __restrict__ C, int lda, int ldb, int ldc, int kseg, int epi)
{
  __shared__ __align__(16) __bf16 lds[2][4][128 * 32];

  const int tid = threadIdx.x;
  const int lane = tid & 63;
  const int laneL = lane & 15;
  const int laneH = lane >> 4;
  const int wave = tid >> 6;
  const int wm = wave >> 1;
  const int wn = wave & 1;
  const int row0 = blockIdx.y * 128;
  const int col0 = blockIdx.x * 128;
  const int k0base = blockIdx.z * kseg;

  const __bf16* src = (wave == 0) ? (const __bf16*)Af : (wave == 1) ? Ab
                    : (wave == 2) ? (const __bf16*)Bf : Br;
  const int srcLd = (wave < 2) ? lda : ldb;
  const int srcRow0 = (wave < 2) ? row0 : col0;
  const int lr = lane >> 2;
  const int ls = lane & 3;
  const int ksl = (ls ^ ((lr >> 1) & 3)) * 8;
  const __bf16* gbase = src + (size_t)(srcRow0 + lr) * srcLd + ksl;

  const int rsw = (laneL >> 1) & 3;
  f32x4 acc[4][4] = {};
  const int nk = kseg >> 5;

  {
    const __bf16* g = gbase + k0base;
    __bf16* dst = &lds[0][wave][lane * 8];
#pragma unroll
    for (int i = 0; i < 8; i++)
      gload16(g + (size_t)i * 16 * srcLd, dst + i * 512);
  }

  int cur = 0;
  for (int t = 0; t < nk; t++) {
    if (t + 1 < nk) {
      const __bf16* g = gbase + k0base + (t + 1) * 32;
      __bf16* dst = &lds[cur ^ 1][wave][lane * 8];
#pragma unroll
      for (int i = 0; i < 8; i++)
        gload16(g + (size_t)i * 16 * srcLd, dst + i * 512);
      asm volatile("s_waitcnt vmcnt(8)" ::: "memory");
    } else {
      asm volatile("s_waitcnt vmcnt(0)" ::: "memory");
    }
    __builtin_amdgcn_s_barrier();
    __builtin_amdgcn_sched_barrier(0);

    const _Float16* sAf = (const _Float16*)lds[cur][0];
    const __bf16*   sAb = lds[cur][1];
    const _Float16* sBf = (const _Float16*)lds[cur][2];
    const __bf16*   sBr = lds[cur][3];

    f16x8 af[4], bf[4]; bf16x8 ab[4], br[4];
#pragma unroll
    for (int i = 0; i < 4; i++) {
      int off = (wm * 64 + i * 16 + laneL) * 32 + ((laneH ^ rsw) << 3);
      af[i] = *(const f16x8*)&sAf[off];
      ab[i] = *(const bf16x8*)&sAb[off];
    }
#pragma unroll
    for (int j = 0; j < 4; j++) {
      int off = (wn * 64 + j * 16 + laneL) * 32 + ((laneH ^ rsw) << 3);
      bf[j] = *(const f16x8*)&sBf[off];
      br[j] = *(const bf16x8*)&sBr[off];
    }
#pragma unroll
    for (int i = 0; i < 4; i++)
#pragma unroll
      for (int j = 0; j < 4; j++) {
        acc[i][j] = __builtin_amdgcn_mfma_f32_16x16x32_f16(af[i], bf[j], acc[i][j], 0, 0, 0);
        acc[i][j] = __builtin_amdgcn_mfma_f32_16x16x32_bf16(ab[i], br[j], acc[i][j], 0, 0, 0);
      }
    __builtin_amdgcn_sched_barrier(0);
    __builtin_amdgcn_s_barrier();
    cur ^= 1;
  }

  float* Cz = C + (size_t)blockIdx.z * gridDim.y * 128 * ldc;
#pragma unroll
  for (int i = 0; i < 4; i++) {
    int rr = row0 + wm * 64 + i * 16 + laneH * 4;
#pragma unroll
    for (int j = 0; j < 4; j++) {
      int cc = col0 + wn * 64 + j * 16 + laneL;
#pragma unroll
      for (int r = 0; r < 4; r++) {
        float v = acc[i][j][r];
        if (epi == 1) v = (v > 20.f) ? v : log1pf(expf(v));
        Cz[(size_t)(rr + r) * ldc + cc] = v;
      }
    }
  }
}

// ---------------- split-K reduce (x_proj only) ----------------
__global__ __launch_bounds__(256) void reduce_xproj(
    const float* __restrict__ part, float* __restrict__ x_dbl,
    _Float16* __restrict__ dtf, __bf16* __restrict__ dtb)
{
  int idx = blockIdx.x * 256 + threadIdx.x;   // 0 .. 4096*128-1
  int row = idx >> 7, col = idx & 127;
  float v = 0.f;
#pragma unroll
  for (int s = 0; s < 8; s++) v += part[(size_t)s * 524288 + idx];
  if (col < 96) x_dbl[(size_t)row * 96 + col] = v;
  if (col < 64) {
    dtf[(size_t)row * 64 + col] = (_Float16)v;
    dtb[(size_t)row * 64 + col] = (__bf16)v;
  }
}

// ---------------------------------------------------------------------------
// Depthwise causal conv (K=4) + bias + silu, strip-tiled.
// ---------------------------------------------------------------------------
__global__ __launch_bounds__(256) void conv_silu_k(
    const float* __restrict__ xz, const float* __restrict__ conv_w,
    const float* __restrict__ conv_b, float* __restrict__ x,
    _Float16* __restrict__ xf, __bf16* __restrict__ xb)
{
  __shared__ __align__(16) float s[35][256];

  const int tid = threadIdx.x;
  const int d0 = blockIdx.x * 256;
  const int l0 = blockIdx.y * 32;
  const int b = blockIdx.z;
  const size_t brow = (size_t)b * 1024;

  for (int u = tid; u < 2240; u += 256) {
    int r = u >> 6;
    int c4 = (u & 63) * 4;
    int gl = l0 - 3 + r;
    float4 v = make_float4(0.f, 0.f, 0.f, 0.f);
    if (gl >= 0)
      v = *(const float4*)&xz[(brow + gl) * 4096 + d0 + c4];
    *(float4*)&s[r][c4] = v;
  }
  __syncthreads();

  const int d = d0 + tid;
  const float4 w = ((const float4*)conv_w)[d];
  const float bias = conv_b[d];
#pragma unroll 4
  for (int lt = 0; lt < 32; lt++) {
    float acc = bias;
    acc = fmaf(s[lt][tid],     w.x, acc);
    acc = fmaf(s[lt + 1][tid], w.y, acc);
    acc = fmaf(s[lt + 2][tid], w.z, acc);
    acc = fmaf(s[lt + 3][tid], w.w, acc);
    float sv = acc / (1.f + expf(-acc));
    size_t o = (brow + l0 + lt) * 2048 + d;
    x[o] = sv;
    xf[o] = (_Float16)sv;
    xb[o] = (__bf16)sv;
  }
}

// ---------------- chunked selective scan ----------------
#define NCHK 32
#define LC   32
#define DB   64
#define LOG2E 1.44269504f

__global__ __launch_bounds__(256) void scan_chunk1(
    const float* __restrict__ delta, const float* __restrict__ x,
    const float* __restrict__ x_dbl, const float* __restrict__ A_log,
    float* __restrict__ Bacc, float* __restrict__ sdsum)
{
  __shared__ __align__(16) float sdel[LC][DB];
  __shared__ __align__(16) float sx[LC][DB];
  __shared__ __align__(16) float sB[LC][16];

  const int tid = threadIdx.x;
  const int dl = tid >> 2;
  const int ng = tid & 3;
  const int d0 = blockIdx.x * DB;
  const int c = blockIdx.y, b = blockIdx.z;
  const int d = d0 + dl;
  const size_t row0 = (size_t)b * 1024 + c * LC;

  float a2[4];
#pragma unroll
  for (int i = 0; i < 4; i++) a2[i] = -expf(A_log[d * 16 + ng * 4 + i]) * LOG2E;

#pragma unroll
  for (int i = 0; i < 2; i++) {
    int f = tid + i * 256;
    int lr = f >> 4, c4 = (f & 15) * 4;
    size_t g = (row0 + lr) * 2048 + d0 + c4;
    *(float4*)&sdel[lr][c4] = *(const float4*)&delta[g];
    *(float4*)&sx[lr][c4]   = *(const float4*)&x[g];
  }
  if (tid < 128) {
    int lr = tid >> 2, n4 = (tid & 3) * 4;
    *(float4*)&sB[lr][n4] = *(const float4*)&x_dbl[(row0 + lr) * 96 + 64 + n4];
  }
  __syncthreads();

  float q0 = 0.f, q1 = 0.f, q2 = 0.f, q3 = 0.f, sd = 0.f;
#pragma unroll
  for (int t = 0; t < LC; t++) {
    float dlt = sdel[t][dl];
    float dx = dlt * sx[t][dl];
    const float4 Bv = *(const float4*)&sB[t][ng * 4];
    q0 = exp2f(dlt * a2[0]) * q0 + dx * Bv.x;
    q1 = exp2f(dlt * a2[1]) * q1 + dx * Bv.y;
    q2 = exp2f(dlt * a2[2]) * q2 + dx * Bv.z;
    q3 = exp2f(dlt * a2[3]) * q3 + dx * Bv.w;
    sd += dlt;
  }
  size_t o = ((size_t)(b * NCHK + c) * 2048 + d) * 16 + ng * 4;
  *(float4*)&Bacc[o] = make_float4(q0, q1, q2, q3);
  if (ng == 0) sdsum[(size_t)(b * NCHK + c) * 2048 + d] = sd;
}

__global__ __launch_bounds__(256) void scan_chunk2(
    const float* __restrict__ A_log, const float* __restrict__ sdsum,
    float* __restrict__ BaccH)
{
  const int g = blockIdx.x * 256 + threadIdx.x;
  const int ng = g & 3;
  const int d = (g >> 2) & 2047;
  const int b = g >> 13;
  float a2[4];
#pragma unroll
  for (int i = 0; i < 4; i++) a2[i] = -expf(A_log[d * 16 + ng * 4 + i]) * LOG2E;
  float h0 = 0.f, h1 = 0.f, h2 = 0.f, h3 = 0.f;
#pragma unroll 4
  for (int c = 0; c < NCHK; c++) {
    size_t o = ((size_t)(b * NCHK + c) * 2048 + d) * 16 + ng * 4;
    const float4 Q = *(const float4*)&BaccH[o];
    const float sd = sdsum[(size_t)(b * NCHK + c) * 2048 + d];
    *(float4*)&BaccH[o] = make_float4(h0, h1, h2, h3);
    h0 = exp2f(sd * a2[0]) * h0 + Q.x;
    h1 = exp2f(sd * a2[1]) * h1 + Q.y;
    h2 = exp2f(sd * a2[2]) * h2 + Q.z;
    h3 = exp2f(sd * a2[3]) * h3 + Q.w;
  }
}

__global__ __launch_bounds__(256) void scan_chunk3(
    const float* __restrict__ delta, const float* __restrict__ x,
    const float* __restrict__ xz, const float* __restrict__ x_dbl,
    const float* __restrict__ A_log, const float* __restrict__ Dvec,
    const float* __restrict__ Hstart,
    _Float16* __restrict__ yf, __bf16* __restrict__ yb)
{
  __shared__ __align__(16) float sdel[LC][DB];
  __shared__ __align__(16) float sx[LC][DB];
  __shared__ __align__(16) float szo[LC][DB];
  __shared__ __align__(16) float sB[LC][16];
  __shared__ __align__(16) float sC[LC][16];

  const int tid = threadIdx.x;
  const int dl = tid >> 2;
  const int ng = tid & 3;
  const int d0 = blockIdx.x * DB;
  const int c = blockIdx.y, b = blockIdx.z;
  const int d = d0 + dl;
  const size_t row0 = (size_t)b * 1024 + c * LC;

  float a2[4];
#pragma unroll
  for (int i = 0; i < 4; i++) a2[i] = -expf(A_log[d * 16 + ng * 4 + i]) * LOG2E;
  const float Dd = Dvec[d];

#pragma unroll
  for (int i = 0; i < 2; i++) {
    int f = tid + i * 256;
    int lr = f >> 4, c4 = (f & 15) * 4;
    size_t g = (row0 + lr) * 2048 + d0 + c4;
    *(float4*)&sdel[lr][c4] = *(const float4*)&delta[g];
    *(float4*)&sx[lr][c4]   = *(const float4*)&x[g];
    *(float4*)&szo[lr][c4]  = *(const float4*)&xz[(row0 + lr) * 4096 + 2048 + d0 + c4];
  }
  {
    int which = tid >> 7;
    int f = tid & 127;
    int lr = f >> 2, n4 = (f & 3) * 4;
    float4 v = *(const float4*)&x_dbl[(row0 + lr) * 96 + 64 + which * 16 + n4];
    if (which == 0) *(float4*)&sB[lr][n4] = v;
    else            *(float4*)&sC[lr][n4] = v;
  }
  __syncthreads();

  size_t ho = ((size_t)(b * NCHK + c) * 2048 + d) * 16 + ng * 4;
  const float4 hv = *(const float4*)&Hstart[ho];
  float h0 = hv.x, h1 = hv.y, h2 = hv.z, h3 = hv.w;

#pragma unroll
  for (int t = 0; t < LC; t++) {
    float dlt = sdel[t][dl];
    float xv = sx[t][dl];
    float dx = dlt * xv;
    const float4 Bv = *(const float4*)&sB[t][ng * 4];
    const float4 Cv = *(const float4*)&sC[t][ng * 4];
    float acc;
    h0 = exp2f(dlt * a2[0]) * h0 + dx * Bv.x; acc  = h0 * Cv.x;
    h1 = exp2f(dlt * a2[1]) * h1 + dx * Bv.y; acc += h1 * Cv.y;
    h2 = exp2f(dlt * a2[2]) * h2 + dx * Bv.z; acc += h2 * Cv.z;
    h3 = exp2f(dlt * a2[3]) * h3 + dx * Bv.w; acc += h3 * Cv.w;
    acc += __shfl_xor(acc, 1);
    acc += __shfl_xor(acc, 2);
    if (ng == 0) {
      float zv = szo[t][dl];
      szo[t][dl] = (acc + xv * Dd) * (zv / (1.f + expf(-zv)));
    }
  }
  __syncthreads();
#pragma unroll
  for (int i = 0; i < 2; i++) {
    int f = tid + i * 256;
    int lr = f >> 4, c4 = (f & 15) * 4;
    float4 v = *(const float4*)&szo[lr][c4];
    f16x4 vf; bf16x4 vb;
    cvt_act4(v, vf, vb);
    size_t o = (row0 + lr) * 2048 + d0 + c4;
    *(f16x4*)&yf[o] = vf;
    *(bf16x4*)&yb[o] = vb;
  }
}

extern "C" void kernel_launch(void* const* d_in, const int* in_sizes, int n_in,
                              void* d_out, int out_size, void* d_ws, size_t ws_size,
                              hipStream_t stream)
{
  const float* hidden     = (const float*)d_in[0];
  const float* in_proj_w  = (const float*)d_in[1];
  const float* conv_w     = (const float*)d_in[2];
  const float* conv_b     = (const float*)d_in[3];
  const float* x_proj_w   = (const float*)d_in[4];
  const float* dt_proj_w  = (const float*)d_in[5];
  const float* A_log      = (const float*)d_in[6];
  const float* Dvec       = (const float*)d_in[7];
  const float* out_proj_w = (const float*)d_in[8];
  float* out = (float*)d_out;

  // ---- workspace arena (f32 element offsets); aliased regions noted ----
  float* w = (float*)d_ws;
  float* xz    = w;                         // 16,777,216   [gemm1 .. scan3]
  float* x     = xz + 16777216;             //  8,388,608
  float* x_dbl = x + 8388608;               //    393,216
  float* dreg  = x_dbl + 393216;            //  8,388,608   hid/inw cvt -> xf/xb -> delta
  float* Breg  = dreg + 8388608;            //  4,194,304   xp_part -> Bacc
  float* sdsum = Breg + 4194304;            //    262,144
  float* Dreg  = sdsum + 262144;            //  8,388,608   yf/yb
  float* wsm   = Dreg + 8388608;            //  2,752,512   small weights

  __bf16* d16 = (__bf16*)dreg;
  _Float16* hid_f = (_Float16*)d16;              // 4,194,304 elems
  __bf16*   hid_b = d16 + 4194304;
  _Float16* inw_f = (_Float16*)(d16 + 8388608);
  __bf16*   inw_r = d16 + 12582912;
  _Float16* xf    = (_Float16*)d16;              // after gemm1 (hid/inw dead)
  __bf16*   xb    = d16 + 8388608;
  float*  delta   = dreg;                        // f32 (after x_proj)
  float*  xp_part = Breg;                        // 8 x 524,288
  float*  Bacc    = Breg;                        // (after reduce_xproj)
  _Float16* yf = (_Float16*)Dreg;
  __bf16*   yb = (__bf16*)Dreg + 8388608;

  __bf16* wm16 = (__bf16*)wsm;
  _Float16* xpw_f = (_Float16*)wm16;             // 128*2048 (rows 96..127 zero)
  __bf16*   xpw_r = wm16 + 262144;
  _Float16* dtw_f = (_Float16*)(wm16 + 524288);  // 2048*64
  __bf16*   dtw_r = wm16 + 655360;
  _Float16* dtf   = (_Float16*)(wm16 + 786432);  // 4096*64
  __bf16*   dtb   = wm16 + 1048576;
  _Float16* ow_f  = (_Float16*)(wm16 + 1310720); // 1024*2048
  __bf16*   ow_r  = wm16 + 3407872;

  // ---- single fused conversion pass ----
  cvt_all<<<10624, 256, 0, stream>>>(hidden, in_proj_w, x_proj_w, dt_proj_w,
                                     out_proj_w, hid_f, hid_b, inw_f, inw_r,
                                     xpw_f, xpw_r, dtw_f, dtw_r, ow_f, ow_r);

  // xz = hidden @ in_proj_w^T   (M=4096, N=4096, K=1024) — 256x256 blocks
  gemm256<<<dim3(16, 16, 1), 512, 131072, stream>>>(hid_f, hid_b, inw_f, inw_r,
                                                    xz, 1024, 1024, 4096, 1024);
  // x = silu(conv(x_pre) + b), + fp16/bf16 copies (strip-tiled)
  conv_silu_k<<<dim3(8, 32, 4), 256, 0, stream>>>(xz, conv_w, conv_b, x, xf, xb);
  // x_dbl partials = x @ x_proj_w^T  (split-K S=8, kseg=256, padded N=128)
  gemm3<<<dim3(1, 32, 8), 256, 0, stream>>>(xf, xb, xpw_f, xpw_r, xp_part,
                                            2048, 2048, 128, 256, 0);
  reduce_xproj<<<2048, 256, 0, stream>>>(xp_part, x_dbl, dtf, dtb);
  // delta = softplus(dt @ dt_proj_w^T)  (K=64)
  gemm3<<<dim3(16, 32, 1), 256, 0, stream>>>(dtf, dtb, dtw_f, dtw_r, delta,
                                             64, 64, 2048, 64, 1);
  // chunked selective scan (writes y as fp16 + bf16)
  scan_chunk1<<<dim3(32, NCHK, 4), 256, 0, stream>>>(delta, x, x_dbl, A_log, Bacc, sdsum);
  scan_chunk2<<<128, 256, 0, stream>>>(A_log, sdsum, Bacc);
  scan_chunk3<<<dim3(32, NCHK, 4), 256, 0, stream>>>(delta, x, xz, x_dbl, A_log, Dvec,
                                                     Bacc, yf, yb);
  // out = y @ out_proj_w^T  (M=4096, N=1024, K=2048) — 128^2 S=1, direct write
  gemm3<<<dim3(8, 32, 1), 256, 0, stream>>>(yf, yb, ow_f, ow_r, out,
                                            2048, 2048, 1024, 2048, 0);
}